// Round 4
// baseline (1564.447 us; speedup 1.0000x reference)
//
#include <hip/hip_runtime.h>
#include <math.h>

#define EPS   1e-5f
#define NB    32
#define NSEQ  197
#define DIM   384
#define NH    12
#define HD    32
#define HIDC  36
#define MLPH  1536
#define NN2   38809          // 197*197
#define NROWS 6304           // 32*197
#define NPIX  1241888        // 32*38809
#define XSIZE 2420736        // 32*197*384 — exact size of output 0
#define SQF   0.4204482076268572f   // 32^(-0.25)

// ---- stats scratch layout (floats, inside ws) ----
#define ST_MOMSUM  0      // 12
#define ST_MOMPROD 16     // 144 (i<=j at i*12+j)
#define ST_SC1     160    // 36
#define ST_SH1     200    // 36
#define ST_S2      256    // 64*36
#define ST_SS2     2560   // 64*36
#define ST_SC2     4864   // 36
#define ST_SH2     4900   // 36
#define ST_P3      4992   // 64*60  ([slot][s*12+c])
#define ST_ABG     8832   // 36 (alpha,beta,gamma)
#define ST_TOTAL   8896

// ---- workspace offsets (floats) ----  total ~108 MB
// (spacings are >= the region sizes; small gaps are intentional slack)
#define O_H     0ull
#define O_Q     2421504ull
#define O_K     4843008ull
#define O_V     7264512ull
#define O_ATT0  9686016ull        // 14902656 floats
#define O_X1    24588672ull
#define O_STATS 27010176ull
#define WS_FLOATS (O_STATS + ST_TOTAL)

// ============================ LayerNorm (x*0.5) ============================
__global__ __launch_bounds__(384) void k_ln(const float* __restrict__ xin,
                                            const float* __restrict__ g,
                                            const float* __restrict__ bb,
                                            float* __restrict__ hout) {
    const int r = blockIdx.x;
    const int t = threadIdx.x;
    float v = xin[(size_t)r * DIM + t] * 0.5f;
    float s = v, sq = v * v;
#pragma unroll
    for (int off = 32; off >= 1; off >>= 1) {
        s  += __shfl_xor(s, off);
        sq += __shfl_xor(sq, off);
    }
    __shared__ float ls[6], lq[6];
    __shared__ float mv[2];
    const int wid = t >> 6;
    if ((t & 63) == 0) { ls[wid] = s; lq[wid] = sq; }
    __syncthreads();
    if (t == 0) {
        float S = 0.f, Q = 0.f;
        for (int i = 0; i < 6; ++i) { S += ls[i]; Q += lq[i]; }
        float m = S / (float)DIM;
        mv[0] = m;
        mv[1] = rsqrtf(Q / (float)DIM - m * m + EPS);
    }
    __syncthreads();
    hout[(size_t)r * DIM + t] = (v - mv[0]) * mv[1] * g[t] + bb[t];
}

// ============================ 128x128 fp32 GEMM core (A[M][K] @ B[N][K]^T) =
template <int KDIM>
__device__ __forceinline__ void gemm128(const float* __restrict__ A,
                                        const float* __restrict__ Bw,
                                        int M, int row0, int col0,
                                        float (&acc)[8][8]) {
    __shared__ float As[16][132];
    __shared__ float Bs[16][132];
    const int tid = threadIdx.x;
    const int lk = tid & 15, lr = tid >> 4;
    const int tx = tid & 15, ty = tid >> 4;
    for (int k0 = 0; k0 < KDIM; k0 += 16) {
#pragma unroll
        for (int i = 0; i < 8; ++i) {
            int r = row0 + lr + 16 * i;
            As[lk][lr + 16 * i] = (r < M) ? A[(size_t)r * KDIM + k0 + lk] : 0.f;
            Bs[lk][lr + 16 * i] = Bw[(size_t)(col0 + lr + 16 * i) * KDIM + k0 + lk];
        }
        __syncthreads();
#pragma unroll
        for (int kk = 0; kk < 16; ++kk) {
            float av[8], bv[8];
            *(float4*)&av[0] = *(const float4*)&As[kk][ty * 8];
            *(float4*)&av[4] = *(const float4*)&As[kk][ty * 8 + 4];
            *(float4*)&bv[0] = *(const float4*)&Bs[kk][tx * 8];
            *(float4*)&bv[4] = *(const float4*)&Bs[kk][tx * 8 + 4];
#pragma unroll
            for (int i = 0; i < 8; ++i)
#pragma unroll
                for (int j = 0; j < 8; ++j)
                    acc[i][j] = fmaf(av[i], bv[j], acc[i][j]);
        }
        __syncthreads();
    }
}

// ============================ QKV GEMM + scatter =========================
__global__ __launch_bounds__(256) void k_qkv(const float* __restrict__ h,
                                             const float* __restrict__ w,
                                             float* __restrict__ q,
                                             float* __restrict__ kx,
                                             float* __restrict__ v) {
    float acc[8][8] = {};
    const int row0 = blockIdx.y * 128, col0 = blockIdx.x * 128;
    gemm128<DIM>(h, w, NROWS, row0, col0, acc);
    const int tx = threadIdx.x & 15, ty = threadIdx.x >> 4;
#pragma unroll
    for (int i = 0; i < 8; ++i) {
        int r = row0 + ty * 8 + i;
        if (r >= NROWS) break;
        int b = r / NSEQ, n = r - b * NSEQ;
#pragma unroll
        for (int j = 0; j < 8; ++j) {
            int o = col0 + tx * 8 + j;
            int sec = o / DIM;
            int hh = (o >> 5) % NH;
            int dd = o & 31;
            float val = acc[i][j];
            float* dst = (sec == 0) ? q : ((sec == 1) ? kx : v);
            if (sec < 2) val *= SQF;
            dst[((size_t)(b * NH + hh) * NSEQ + n) * HD + dd] = val;
        }
    }
}

// ============================ proj GEMM + residual =======================
__global__ __launch_bounds__(256) void k_proj(const float* __restrict__ outm,
                                              const float* __restrict__ w,
                                              const float* __restrict__ pb,
                                              const float* __restrict__ x0,
                                              float* __restrict__ x1) {
    float acc[8][8] = {};
    const int row0 = blockIdx.y * 128, col0 = blockIdx.x * 128;
    gemm128<DIM>(outm, w, NROWS, row0, col0, acc);
    const int tx = threadIdx.x & 15, ty = threadIdx.x >> 4;
#pragma unroll
    for (int i = 0; i < 8; ++i) {
        int r = row0 + ty * 8 + i;
        if (r >= NROWS) break;
#pragma unroll
        for (int j = 0; j < 8; ++j) {
            int o = col0 + tx * 8 + j;
            x1[(size_t)r * DIM + o] = x0[(size_t)r * DIM + o] + 2.f * (acc[i][j] + pb[o]);
        }
    }
}

// ============================ fc1 GEMM + exact GELU ======================
__global__ __launch_bounds__(256) void k_fc1(const float* __restrict__ h,
                                             const float* __restrict__ w,
                                             const float* __restrict__ fb,
                                             float* __restrict__ m1) {
    float acc[8][8] = {};
    const int row0 = blockIdx.y * 128, col0 = blockIdx.x * 128;
    gemm128<DIM>(h, w, NROWS, row0, col0, acc);
    const int tx = threadIdx.x & 15, ty = threadIdx.x >> 4;
#pragma unroll
    for (int i = 0; i < 8; ++i) {
        int r = row0 + ty * 8 + i;
        if (r >= NROWS) break;
#pragma unroll
        for (int j = 0; j < 8; ++j) {
            int o = col0 + tx * 8 + j;
            float z = acc[i][j] + fb[o];
            m1[(size_t)r * MLPH + o] = 0.5f * z * (1.f + erff(z * 0.70710678118654752f));
        }
    }
}

// ============================ fc2 GEMM + scale + residual ================
__global__ __launch_bounds__(256) void k_fc2(const float* __restrict__ m1,
                                             const float* __restrict__ w,
                                             const float* __restrict__ fb,
                                             const float* __restrict__ scch,
                                             const float* __restrict__ x1,
                                             float* __restrict__ xout) {
    float acc[8][8] = {};
    const int row0 = blockIdx.y * 128, col0 = blockIdx.x * 128;
    gemm128<MLPH>(m1, w, NROWS, row0, col0, acc);
    const int tx = threadIdx.x & 15, ty = threadIdx.x >> 4;
#pragma unroll
    for (int i = 0; i < 8; ++i) {
        int r = row0 + ty * 8 + i;
        if (r >= NROWS) break;
#pragma unroll
        for (int j = 0; j < 8; ++j) {
            int o = col0 + tx * 8 + j;
            xout[(size_t)r * DIM + o] =
                x1[(size_t)r * DIM + o] + 2.f * (acc[i][j] + fb[o]) * scch[o];
        }
    }
}

// ============================ scores + softmax ===========================
__global__ __launch_bounds__(256) void k_score(const float* __restrict__ q,
                                               const float* __restrict__ kmat,
                                               float* __restrict__ att) {
    __shared__ float Ks[NSEQ][36];
    __shared__ float Qs[16][36];
    const int bh = blockIdx.y;
    const int y0 = blockIdx.x * 16;
    const size_t kb = (size_t)bh * (NSEQ * HD);
    for (int i = threadIdx.x; i < NSEQ * HD; i += 256) Ks[i >> 5][i & 31] = kmat[kb + i];
    for (int i = threadIdx.x; i < 16 * HD; i += 256) {
        int rr = i >> 5, dd = i & 31, yy = y0 + rr;
        Qs[rr][dd] = (yy < NSEQ) ? q[kb + (size_t)yy * HD + dd] : 0.f;
    }
    __syncthreads();
    const int tx = threadIdx.x & 15, ty = threadIdx.x >> 4;
    const int y = y0 + ty;
    if (y >= NSEQ) return;
    float qr[32];
#pragma unroll
    for (int wq = 0; wq < 8; ++wq) *(float4*)&qr[wq * 4] = *(const float4*)&Qs[ty][wq * 4];
    float sc[13];
    float mx = -1e30f;
#pragma unroll
    for (int m = 0; m < 13; ++m) {
        int x = tx + m * 16;
        float d = -1e30f;
        if (x < NSEQ) {
            const float4* kp = (const float4*)&Ks[x][0];
            float a = 0.f;
#pragma unroll
            for (int wq = 0; wq < 8; ++wq) {
                float4 kv = kp[wq];
                a = fmaf(qr[wq * 4 + 0], kv.x, a);
                a = fmaf(qr[wq * 4 + 1], kv.y, a);
                a = fmaf(qr[wq * 4 + 2], kv.z, a);
                a = fmaf(qr[wq * 4 + 3], kv.w, a);
            }
            d = a;
        }
        sc[m] = d;
        mx = fmaxf(mx, d);
    }
#pragma unroll
    for (int off = 8; off >= 1; off >>= 1) mx = fmaxf(mx, __shfl_xor(mx, off, 16));
    float ssum = 0.f;
#pragma unroll
    for (int m = 0; m < 13; ++m) {
        int x = tx + m * 16;
        float e = (x < NSEQ) ? __expf(sc[m] - mx) : 0.f;
        sc[m] = e;
        ssum += e;
    }
#pragma unroll
    for (int off = 8; off >= 1; off >>= 1) ssum += __shfl_xor(ssum, off, 16);
    const float rinv = 1.f / ssum;
    const size_t ab = (size_t)bh * NN2 + (size_t)y * NSEQ;
#pragma unroll
    for (int m = 0; m < 13; ++m) {
        int x = tx + m * 16;
        if (x < NSEQ) att[ab + x] = sc[m] * rinv;
    }
}

// ============================ channel moments of attn0 ===================
__global__ __launch_bounds__(256) void k_moments(const float* __restrict__ att,
                                                 float* __restrict__ stats) {
    float mu[12] = {};
    float pr[78] = {};
    const int stride = gridDim.x * 256;
    for (int p = blockIdx.x * 256 + threadIdx.x; p < NPIX; p += stride) {
        int b = p / NN2;
        int s = p - b * NN2;
        const float* base = att + (size_t)b * 12 * NN2 + s;
        float v[12];
#pragma unroll
        for (int i = 0; i < 12; ++i) v[i] = base[(size_t)i * NN2];
#pragma unroll
        for (int i = 0; i < 12; ++i) mu[i] += v[i];
#pragma unroll
        for (int i = 0; i < 12; ++i)
#pragma unroll
            for (int j = i; j < 12; ++j)
                pr[i * (23 - i) / 2 + j] += v[i] * v[j];
    }
#pragma unroll
    for (int s = 0; s < 12; ++s)
#pragma unroll
        for (int off = 32; off >= 1; off >>= 1) mu[s] += __shfl_xor(mu[s], off);
#pragma unroll
    for (int s = 0; s < 78; ++s)
#pragma unroll
        for (int off = 32; off >= 1; off >>= 1) pr[s] += __shfl_xor(pr[s], off);
    __shared__ float red[4][90];
    const int lane = threadIdx.x & 63, wid = threadIdx.x >> 6;
    if (lane == 0) {
#pragma unroll
        for (int s = 0; s < 12; ++s) red[wid][s] = mu[s];
#pragma unroll
        for (int s = 0; s < 78; ++s) red[wid][12 + s] = pr[s];
    }
    __syncthreads();
    const int t = threadIdx.x;
    if (t < 90) {
        float tot = red[0][t] + red[1][t] + red[2][t] + red[3][t];
        int addr;
        if (t < 12) addr = ST_MOMSUM + t;
        else {
            int tt = t - 12;
            int i = 0;
            while (tt >= 12 - i) { tt -= 12 - i; ++i; }
            addr = ST_MOMPROD + i * 12 + (i + tt);
        }
        atomicAdd(&stats[addr], tot);
    }
}

// ============================ finalize bn1 (analytic) ====================
__global__ __launch_bounds__(64) void k_fin1(const float* __restrict__ wexp,
                                             const float* __restrict__ g1,
                                             const float* __restrict__ b1,
                                             float* __restrict__ stats) {
    int o = threadIdx.x;
    if (o >= 36) return;
    const float invM = 1.f / (float)NPIX;
    float mu[12];
#pragma unroll
    for (int i = 0; i < 12; ++i) mu[i] = stats[ST_MOMSUM + i] * invM;
    float mean = 0.f;
#pragma unroll
    for (int i = 0; i < 12; ++i) mean += wexp[o * 12 + i] * mu[i];
    float e2 = 0.f;
    for (int i = 0; i < 12; ++i)
        for (int j = 0; j < 12; ++j) {
            int a = i < j ? i : j, bj = i < j ? j : i;
            e2 += wexp[o * 12 + i] * wexp[o * 12 + j] * stats[ST_MOMPROD + a * 12 + bj] * invM;
        }
    float var = e2 - mean * mean;
    float sc = g1[o] * rsqrtf(var + EPS);
    stats[ST_SC1 + o] = sc;
    stats[ST_SH1 + o] = b1[o] - mean * sc;
}

// ====== PASS A: recompute expand+bn1+relu6+dw, accumulate bn2 sums =======
__global__ __launch_bounds__(256) void k_sums2(const float* __restrict__ att,
                                               const float* __restrict__ wexp,
                                               const float* __restrict__ dww,
                                               const float* __restrict__ stats,
                                               float* __restrict__ statw) {
    __shared__ float a0s[12][256];
    __shared__ float b1s[36][256];
    __shared__ float wexps[432];
    __shared__ float dws[324];
    __shared__ float sc1s[36], sh1s[36];
    __shared__ float sS[4][36], sQ[4][36];
    const int b = blockIdx.z;
    const int oy0 = blockIdx.y * 14, ox0 = blockIdx.x * 14;
    const int tid = threadIdx.x;
    for (int i = tid; i < 432; i += 256) wexps[i] = wexp[i];
    for (int i = tid; i < 324; i += 256) dws[i] = dww[i];
    if (tid < 36) { sc1s[tid] = stats[ST_SC1 + tid]; sh1s[tid] = stats[ST_SH1 + tid]; }
    const int lx = tid & 15, ly = tid >> 4;
    const int gy = oy0 - 1 + ly, gx = ox0 - 1 + lx;
    const bool valid = (gy >= 0 && gy < NSEQ && gx >= 0 && gx < NSEQ);
#pragma unroll
    for (int i = 0; i < 12; ++i)
        a0s[i][tid] = valid ? att[(size_t)(b * 12 + i) * NN2 + (size_t)gy * NSEQ + gx] : 0.f;
    __syncthreads();
    float a0v[12];
#pragma unroll
    for (int i = 0; i < 12; ++i) a0v[i] = a0s[i][tid];
#pragma unroll 4
    for (int o = 0; o < 36; ++o) {
        float t = 0.f;
#pragma unroll
        for (int i = 0; i < 12; ++i) t = fmaf(wexps[o * 12 + i], a0v[i], t);
        t = fminf(fmaxf(fmaf(sc1s[o], t, sh1s[o]), 0.f), 6.f);
        b1s[o][tid] = valid ? t : 0.f;
    }
    __syncthreads();
    const bool inter = (ly >= 1 && ly <= 14 && lx >= 1 && lx <= 14 &&
                        gy < NSEQ && gx < NSEQ);
    const int base = inter ? ((ly - 1) * 16 + (lx - 1)) : 0;
    const int lane = tid & 63, wid = tid >> 6;
    for (int o = 0; o < 36; ++o) {
        float s = 0.f;
        if (inter) {
            const float* bp = &b1s[o][base];
#pragma unroll
            for (int dy = 0; dy < 3; ++dy)
#pragma unroll
                for (int dx = 0; dx < 3; ++dx)
                    s = fmaf(dws[o * 9 + dy * 3 + dx], bp[dy * 16 + dx], s);
        }
        float qv = s * s;
#pragma unroll
        for (int off = 32; off >= 1; off >>= 1) {
            s  += __shfl_xor(s, off);
            qv += __shfl_xor(qv, off);
        }
        if (lane == 0) { sS[wid][o] = s; sQ[wid][o] = qv; }
    }
    __syncthreads();
    if (tid < 72) {
        int o = (tid < 36) ? tid : (tid - 36);
        float tot = (tid < 36)
            ? (sS[0][o] + sS[1][o] + sS[2][o] + sS[3][o])
            : (sQ[0][o] + sQ[1][o] + sQ[2][o] + sQ[3][o]);
        int slot = (blockIdx.z * 225 + blockIdx.y * 15 + blockIdx.x) & 63;
        int addr = (tid < 36) ? (ST_S2 + slot * 36 + o)
                              : (ST_SS2 + slot * 36 + o);
        atomicAdd(&statw[addr], tot);
    }
}

__global__ __launch_bounds__(64) void k_fin2(const float* __restrict__ g2,
                                             const float* __restrict__ b2,
                                             float* __restrict__ stats) {
    int o = threadIdx.x;
    if (o >= 36) return;
    float S = 0.f, SS = 0.f;
    for (int sl = 0; sl < 64; ++sl) {
        S += stats[ST_S2 + sl * 36 + o];
        SS += stats[ST_SS2 + sl * 36 + o];
    }
    const float invM = 1.f / (float)NPIX;
    float m = S * invM, var = SS * invM - m * m;
    float sc = g2[o] * rsqrtf(var + EPS);
    stats[ST_SC2 + o] = sc;
    stats[ST_SH2 + o] = b2[o] - m * sc;
}

// ====== PASS B: recompute + bn2 + relu6 + project 36->12 -> a3 only ======
__global__ __launch_bounds__(256) void k_p3(const float* __restrict__ att,
                                            const float* __restrict__ wexp,
                                            const float* __restrict__ dww,
                                            const float* __restrict__ pw,
                                            const float* __restrict__ stats,
                                            float* __restrict__ datt) {
    __shared__ float a0s[12][256];
    __shared__ float b1s[36][256];
    __shared__ float wexps[432];
    __shared__ float dws[324];
    __shared__ float pws[432];
    __shared__ float sc1s[36], sh1s[36], sc2s[36], sh2s[36];
    const int b = blockIdx.z;
    const int oy0 = blockIdx.y * 14, ox0 = blockIdx.x * 14;
    const int tid = threadIdx.x;
    for (int i = tid; i < 432; i += 256) { wexps[i] = wexp[i]; pws[i] = pw[i]; }
    for (int i = tid; i < 324; i += 256) dws[i] = dww[i];
    if (tid < 36) {
        sc1s[tid] = stats[ST_SC1 + tid]; sh1s[tid] = stats[ST_SH1 + tid];
        sc2s[tid] = stats[ST_SC2 + tid]; sh2s[tid] = stats[ST_SH2 + tid];
    }
    const int lx = tid & 15, ly = tid >> 4;
    const int gy = oy0 - 1 + ly, gx = ox0 - 1 + lx;
    const bool valid = (gy >= 0 && gy < NSEQ && gx >= 0 && gx < NSEQ);
#pragma unroll
    for (int i = 0; i < 12; ++i)
        a0s[i][tid] = valid ? att[(size_t)(b * 12 + i) * NN2 + (size_t)gy * NSEQ + gx] : 0.f;
    __syncthreads();
    float a0v[12];
#pragma unroll
    for (int i = 0; i < 12; ++i) a0v[i] = a0s[i][tid];
#pragma unroll 4
    for (int o = 0; o < 36; ++o) {
        float t = 0.f;
#pragma unroll
        for (int i = 0; i < 12; ++i) t = fmaf(wexps[o * 12 + i], a0v[i], t);
        t = fminf(fmaxf(fmaf(sc1s[o], t, sh1s[o]), 0.f), 6.f);
        b1s[o][tid] = valid ? t : 0.f;
    }
    __syncthreads();
    // interior threads: output pixel == own halo pixel (gy,gx)
    if (ly < 1 || ly > 14 || lx < 1 || lx > 14 || gy >= NSEQ || gx >= NSEQ) return;
    const int base = (ly - 1) * 16 + (lx - 1);
    float a3v[12] = {};
#pragma unroll 4
    for (int o = 0; o < 36; ++o) {
        const float* bp = &b1s[o][base];
        float s = 0.f;
#pragma unroll
        for (int dy = 0; dy < 3; ++dy)
#pragma unroll
            for (int dx = 0; dx < 3; ++dx)
                s = fmaf(dws[o * 9 + dy * 3 + dx], bp[dy * 16 + dx], s);
        float t = fminf(fmaxf(fmaf(sc2s[o], s, sh2s[o]), 0.f), 6.f);
#pragma unroll
        for (int c = 0; c < 12; ++c) a3v[c] = fmaf(pws[c * 36 + o], t, a3v[c]);
    }
    const size_t pix = (size_t)gy * NSEQ + gx;
#pragma unroll
    for (int c = 0; c < 12; ++c)
        datt[(size_t)(b * 12 + c) * NN2 + pix] = a3v[c];
}

// ====== 5 sums over (a3, a0) — grid-stride clone of k_moments ============
__global__ __launch_bounds__(256) void k_p3sums(const float* __restrict__ a3,
                                                const float* __restrict__ att0,
                                                float* __restrict__ stats) {
    float st[60] = {};
    const int stride = gridDim.x * 256;
    for (int p = blockIdx.x * 256 + threadIdx.x; p < NPIX; p += stride) {
        int b = p / NN2;
        int s = p - b * NN2;
        const float* a3b = a3 + (size_t)b * 12 * NN2 + s;
        const float* a0b = att0 + (size_t)b * 12 * NN2 + s;
#pragma unroll
        for (int c = 0; c < 12; ++c) {
            float x3 = a3b[(size_t)c * NN2];
            float x0 = a0b[(size_t)c * NN2];
            st[c]      += x3;
            st[12 + c] = fmaf(x3, x3, st[12 + c]);
            st[24 + c] += x0;
            st[36 + c] = fmaf(x0, x0, st[36 + c]);
            st[48 + c] = fmaf(x3, x0, st[48 + c]);
        }
    }
#pragma unroll
    for (int c = 0; c < 60; ++c)
#pragma unroll
        for (int off = 32; off >= 1; off >>= 1) st[c] += __shfl_xor(st[c], off);
    __shared__ float red[4][60];
    const int lane = threadIdx.x & 63, wid = threadIdx.x >> 6;
    if (lane == 0) {
#pragma unroll
        for (int c = 0; c < 60; ++c) red[wid][c] = st[c];
    }
    __syncthreads();
    if (threadIdx.x < 60) {
        float tot = red[0][threadIdx.x] + red[1][threadIdx.x] +
                    red[2][threadIdx.x] + red[3][threadIdx.x];
        int slot = blockIdx.x & 63;
        atomicAdd(&stats[ST_P3 + slot * 60 + threadIdx.x], tot);
    }
}

// ============ finalize bn3 + adapt_bn -> affine alpha/beta/gamma =========
__global__ __launch_bounds__(64) void k_fin3(const float* __restrict__ g3,
                                             const float* __restrict__ b3,
                                             const float* __restrict__ ag,
                                             const float* __restrict__ ab,
                                             float* __restrict__ stats) {
    int c = threadIdx.x;
    if (c >= 12) return;
    float S3 = 0.f, S3q = 0.f, S0 = 0.f, S0q = 0.f, S30 = 0.f;
    for (int sl = 0; sl < 64; ++sl) {
        const float* p = stats + ST_P3 + sl * 60;
        S3 += p[c]; S3q += p[12 + c]; S0 += p[24 + c]; S0q += p[36 + c]; S30 += p[48 + c];
    }
    const float M = (float)NPIX;
    float m3 = S3 / M, v3 = S3q / M - m3 * m3;
    float pp = g3[c] * rsqrtf(v3 + EPS);
    float qq = b3[c] - m3 * pp;
    float my = (pp * S3 + S0) / M + qq;
    float Syq = pp * pp * S3q + S0q + qq * qq * M + 2.f * pp * S30 + 2.f * pp * qq * S3 + 2.f * qq * S0;
    float vy = Syq / M - my * my;
    float rr = ag[c] * rsqrtf(vy + EPS);
    float ss = ab[c] - my * rr;
    stats[ST_ABG + c] = rr * pp;
    stats[ST_ABG + 12 + c] = rr;
    stats[ST_ABG + 24 + c] = rr * qq + ss;
}

// ====== final attn (in-place affine) + AV product ========================
__global__ __launch_bounds__(256) void k_p4(float* __restrict__ datt,
                                            const float* __restrict__ att0,
                                            const float* __restrict__ v,
                                            const float* __restrict__ stats,
                                            float* __restrict__ outm) {
    __shared__ float Vs[NSEQ][36];
    const int bh = blockIdx.y;
    const int b = bh / 12, hh = bh - b * 12;
    const int y0 = blockIdx.x * 16;
    const size_t vb = (size_t)bh * (NSEQ * HD);
    for (int i = threadIdx.x; i < NSEQ * HD; i += 256) Vs[i >> 5][i & 31] = v[vb + i];
    __syncthreads();
    const float alpha = stats[ST_ABG + hh];
    const float beta  = stats[ST_ABG + 12 + hh];
    const float gamma = stats[ST_ABG + 24 + hh];
    const int tx = threadIdx.x & 15, ty = threadIdx.x >> 4;
    const int y = y0 + ty;
    if (y >= NSEQ) return;
    const size_t ab = (size_t)bh * NN2 + (size_t)y * NSEQ;
    float acc[32] = {};
    for (int m = 0; m < 13; ++m) {
        int x = tx + m * 16;
        if (x < NSEQ) {
            float av = alpha * datt[ab + x] + beta * att0[ab + x] + gamma;
            datt[ab + x] = av;
            const float4* vp = (const float4*)&Vs[x][0];
#pragma unroll
            for (int w = 0; w < 8; ++w) {
                float4 vv = vp[w];
                acc[4 * w + 0] = fmaf(av, vv.x, acc[4 * w + 0]);
                acc[4 * w + 1] = fmaf(av, vv.y, acc[4 * w + 1]);
                acc[4 * w + 2] = fmaf(av, vv.z, acc[4 * w + 2]);
                acc[4 * w + 3] = fmaf(av, vv.w, acc[4 * w + 3]);
            }
        }
    }
#pragma unroll
    for (int d = 0; d < 32; ++d)
#pragma unroll
        for (int off = 8; off >= 1; off >>= 1)
            acc[d] += __shfl_xor(acc[d], off, 16);
    if (tx == 0) {
        float4* o4 = (float4*)(outm + ((size_t)b * NSEQ + y) * DIM + hh * HD);
#pragma unroll
        for (int w = 0; w < 8; ++w)
            o4[w] = make_float4(acc[4 * w], acc[4 * w + 1], acc[4 * w + 2], acc[4 * w + 3]);
    }
}

// ========================================================================
extern "C" void kernel_launch(void* const* d_in, const int* in_sizes, int n_in,
                              void* d_out, int out_size, void* d_ws, size_t ws_size,
                              hipStream_t stream) {
    const float* x     = (const float*)d_in[0];
    const float* ln1g  = (const float*)d_in[1];
    const float* ln1b  = (const float*)d_in[2];
    const float* qkvw  = (const float*)d_in[3];
    const float* wexp  = (const float*)d_in[4];
    const float* bn1g  = (const float*)d_in[5];
    const float* bn1b  = (const float*)d_in[6];
    const float* dww   = (const float*)d_in[7];
    const float* bn2g  = (const float*)d_in[8];
    const float* bn2b  = (const float*)d_in[9];
    const float* prow  = (const float*)d_in[10];
    const float* bn3g  = (const float*)d_in[11];
    const float* bn3b  = (const float*)d_in[12];
    const float* abng  = (const float*)d_in[13];
    const float* abnb  = (const float*)d_in[14];
    const float* projw = (const float*)d_in[15];
    const float* projb = (const float*)d_in[16];
    const float* ln2g  = (const float*)d_in[17];
    const float* ln2b  = (const float*)d_in[18];
    const float* fc1w  = (const float*)d_in[19];
    const float* fc1b  = (const float*)d_in[20];
    const float* fc2w  = (const float*)d_in[21];
    const float* fc2b  = (const float*)d_in[22];
    const float* scch  = (const float*)d_in[23];

    if (ws_size < WS_FLOATS * sizeof(float)) return;   // need ~108 MB scratch

    float* W     = (float*)d_ws;
    float* h     = W + O_H;
    float* q     = W + O_Q;
    float* kx    = W + O_K;
    float* v     = W + O_V;
    float* att0  = W + O_ATT0;
    float* x1    = W + O_X1;
    float* stats = W + O_STATS;
    float* m1    = W + O_ATT0;  // alias: att0 dead after k_p4
    float* outm  = W + O_H;     // alias: h dead after k_qkv

    float* xout = (float*)d_out;
    float* datt = xout + XSIZE;   // attn output region starts at 32*197*384 = 2420736

    hipMemsetAsync(stats, 0, ST_TOTAL * sizeof(float), stream);
    k_ln<<<NROWS, 384, 0, stream>>>(x, ln1g, ln1b, h);
    k_qkv<<<dim3(9, 50), 256, 0, stream>>>(h, qkvw, q, kx, v);
    k_score<<<dim3(13, 384), 256, 0, stream>>>(q, kx, att0);
    k_moments<<<256, 256, 0, stream>>>(att0, stats);
    k_fin1<<<1, 64, 0, stream>>>(wexp, bn1g, bn1b, stats);
    k_sums2<<<dim3(15, 15, 32), 256, 0, stream>>>(att0, wexp, dww, stats, stats);
    k_fin2<<<1, 64, 0, stream>>>(bn2g, bn2b, stats);
    k_p3<<<dim3(15, 15, 32), 256, 0, stream>>>(att0, wexp, dww, prow, stats, datt);
    k_p3sums<<<256, 256, 0, stream>>>(datt, att0, stats);
    k_fin3<<<1, 64, 0, stream>>>(bn3g, bn3b, abng, abnb, stats);
    k_p4<<<dim3(13, 384), 256, 0, stream>>>(datt, att0, v, stats, outm);
    k_proj<<<dim3(3, 50), 256, 0, stream>>>(outm, projw, projb, x, x1);
    k_ln<<<NROWS, 384, 0, stream>>>(x1, ln2g, ln2b, h);
    k_fc1<<<dim3(12, 50), 256, 0, stream>>>(h, fc1w, fc1b, m1);
    k_fc2<<<dim3(3, 50), 256, 0, stream>>>(m1, fc2w, fc2b, scch, x1, xout);
}

// Round 5
// 920.568 us; speedup vs baseline: 1.6994x; 1.6994x over previous
//
#include <hip/hip_runtime.h>
#include <math.h>

#define EPS   1e-5f
#define NSEQ  197
#define DIM   384
#define NH    12
#define HD    32
#define MLPH  1536
#define NN2   38809          // 197*197
#define NROWS 6304           // 32*197
#define MPAD  6400           // rows padded to 50*128
#define NPIX  1241888        // 32*38809
#define XSIZE 2420736        // 32*197*384 — exact size of output 0
#define SQF   0.4204482076268572f   // 32^(-0.25)

typedef __bf16 bf16;
typedef __attribute__((ext_vector_type(8))) __bf16 bf16x8;
typedef __attribute__((ext_vector_type(4))) float floatx4;
typedef unsigned int u32;
typedef const __attribute__((address_space(1))) u32* gptr_t;
typedef __attribute__((address_space(3))) u32* lptr_t;

// ---- stats scratch layout (floats, inside ws) ----
#define ST_MOMSUM  0      // 12
#define ST_MOMPROD 16     // 144 (i<=j at i*12+j)
#define ST_SC1     160    // 36
#define ST_SH1     200    // 36
#define ST_S2      256    // 64*36
#define ST_SS2     2560   // 64*36
#define ST_SC2     4864   // 36
#define ST_SH2     4900   // 36
#define ST_P3      4992   // 64*60
#define ST_ABG     8832   // 36 (alpha,beta,gamma)
#define ST_TOTAL   8896

// ---- workspace offsets (float slots) ----  total ~107 MB
#define O_HB    0ull              // bf16 [6400][384]  (h, then outm, then h2)
#define O_Q     1228800ull        // fp32 [32*12][197][32]
#define O_K     3649536ull
#define O_V     6070272ull
#define O_ATT0  8491008ull        // fp32 14902656 floats; m1 (bf16 6400x1536) aliases
#define O_X1    23393664ull       // fp32 2420736
#define O_WQKV  25814400ull       // bf16 1152x384   (221184 slots)
#define O_WPRJ  26035584ull       // bf16 384x384    (73728)
#define O_WFC1  26109312ull       // bf16 1536x384   (294912)
#define O_WFC2  26404224ull       // bf16 384x1536   (294912)
#define O_STATS 26699136ull
#define WS_FLOATS (O_STATS + ST_TOTAL)

// ============================ weight fp32 -> bf16 ========================
__global__ __launch_bounds__(256) void k_cvt(const float* __restrict__ s0,
                                             const float* __restrict__ s1,
                                             const float* __restrict__ s2,
                                             const float* __restrict__ s3,
                                             bf16* __restrict__ d0,
                                             bf16* __restrict__ d1,
                                             bf16* __restrict__ d2,
                                             bf16* __restrict__ d3) {
    const int w = blockIdx.y;
    const float* s = (w == 0) ? s0 : (w == 1) ? s1 : (w == 2) ? s2 : s3;
    bf16* d = (w == 0) ? d0 : (w == 1) ? d1 : (w == 2) ? d2 : d3;
    const int n = (w == 0) ? 442368 : (w == 1) ? 147456 : 589824;
    for (int i = blockIdx.x * 256 + threadIdx.x; i < n; i += gridDim.x * 256)
        d[i] = (bf16)s[i];
}

// ============================ LayerNorm (x*0.5) -> bf16 ==================
__global__ __launch_bounds__(384) void k_ln(const float* __restrict__ xin,
                                            const float* __restrict__ g,
                                            const float* __restrict__ bb,
                                            bf16* __restrict__ hout) {
    const int r = blockIdx.x;
    const int t = threadIdx.x;
    float v = xin[(size_t)r * DIM + t] * 0.5f;
    float s = v, sq = v * v;
#pragma unroll
    for (int off = 32; off >= 1; off >>= 1) {
        s  += __shfl_xor(s, off);
        sq += __shfl_xor(sq, off);
    }
    __shared__ float ls[6], lq[6];
    __shared__ float mv[2];
    const int wid = t >> 6;
    if ((t & 63) == 0) { ls[wid] = s; lq[wid] = sq; }
    __syncthreads();
    if (t == 0) {
        float S = 0.f, Q = 0.f;
        for (int i = 0; i < 6; ++i) { S += ls[i]; Q += lq[i]; }
        float m = S / (float)DIM;
        mv[0] = m;
        mv[1] = rsqrtf(Q / (float)DIM - m * m + EPS);
    }
    __syncthreads();
    hout[(size_t)r * DIM + t] = (bf16)((v - mv[0]) * mv[1] * g[t] + bb[t]);
}

// =============== 128x128 bf16 MFMA GEMM core: C = A[M][K] @ B[N][K]^T ====
// block = 256 thr = 4 waves in 2x2; wave computes 64x64 via 4x4 MFMA 16x16x32.
template <int KDIM>
__device__ __forceinline__ void mgemm(const bf16* __restrict__ A,
                                      const bf16* __restrict__ B,
                                      int row0, int col0,
                                      floatx4 (&acc)[4][4]) {
    __shared__ bf16 As[128 * 32];
    __shared__ bf16 Bs[128 * 32];
    const int tid = threadIdx.x;
    const int lane = tid & 63, wave = tid >> 6;
    const int wy = wave >> 1, wx = wave & 1;
    const int quad = lane >> 4, l15 = lane & 15;
    for (int k0 = 0; k0 < KDIM; k0 += 32) {
#pragma unroll
        for (int i = 0; i < 2; ++i) {
            const int e = (i * 256 + tid) * 8;           // bf16 elem offset in tile
            const int r = e >> 5, kk = e & 31;
            __builtin_amdgcn_global_load_lds(
                (gptr_t)(A + (size_t)(row0 + r) * KDIM + k0 + kk),
                (lptr_t)(As + e), 16, 0, 0);
            __builtin_amdgcn_global_load_lds(
                (gptr_t)(B + (size_t)(col0 + r) * KDIM + k0 + kk),
                (lptr_t)(Bs + e), 16, 0, 0);
        }
        __syncthreads();
        bf16x8 af[4], bfr[4];
#pragma unroll
        for (int mi = 0; mi < 4; ++mi)
            af[mi] = *(const bf16x8*)&As[(wy * 64 + mi * 16 + l15) * 32 + quad * 8];
#pragma unroll
        for (int ni = 0; ni < 4; ++ni)
            bfr[ni] = *(const bf16x8*)&Bs[(wx * 64 + ni * 16 + l15) * 32 + quad * 8];
#pragma unroll
        for (int mi = 0; mi < 4; ++mi)
#pragma unroll
            for (int ni = 0; ni < 4; ++ni)
                acc[mi][ni] = __builtin_amdgcn_mfma_f32_16x16x32_bf16(
                    af[mi], bfr[ni], acc[mi][ni], 0, 0, 0);
        __syncthreads();
    }
}

// D-element (mi,ni,reg): row = row0+wy*64+mi*16+quad*4+reg, col = col0+wx*64+ni*16+l15

// ============================ QKV GEMM + scatter =========================
__global__ __launch_bounds__(256) void k_qkv(const bf16* __restrict__ h,
                                             const bf16* __restrict__ w,
                                             float* __restrict__ q,
                                             float* __restrict__ kx,
                                             float* __restrict__ v) {
    floatx4 acc[4][4] = {};
    const int row0 = blockIdx.y * 128, col0 = blockIdx.x * 128;
    mgemm<DIM>(h, w, row0, col0, acc);
    const int lane = threadIdx.x & 63, wave = threadIdx.x >> 6;
    const int wy = wave >> 1, wx = wave & 1;
    const int quad = lane >> 4, l15 = lane & 15;
#pragma unroll
    for (int mi = 0; mi < 4; ++mi)
#pragma unroll
        for (int reg = 0; reg < 4; ++reg) {
            int r = row0 + wy * 64 + mi * 16 + quad * 4 + reg;
            if (r >= NROWS) continue;
            int b = r / NSEQ, n = r - b * NSEQ;
#pragma unroll
            for (int ni = 0; ni < 4; ++ni) {
                int o = col0 + wx * 64 + ni * 16 + l15;
                int sec = o / DIM;
                int hh = (o >> 5) % NH;
                int dd = o & 31;
                float val = acc[mi][ni][reg];
                float* dst = (sec == 0) ? q : ((sec == 1) ? kx : v);
                if (sec < 2) val *= SQF;
                dst[((size_t)(b * NH + hh) * NSEQ + n) * HD + dd] = val;
            }
        }
}

// ============================ proj GEMM + residual =======================
__global__ __launch_bounds__(256) void k_proj(const bf16* __restrict__ outm,
                                              const bf16* __restrict__ w,
                                              const float* __restrict__ pb,
                                              const float* __restrict__ x0,
                                              float* __restrict__ x1) {
    floatx4 acc[4][4] = {};
    const int row0 = blockIdx.y * 128, col0 = blockIdx.x * 128;
    mgemm<DIM>(outm, w, row0, col0, acc);
    const int lane = threadIdx.x & 63, wave = threadIdx.x >> 6;
    const int wy = wave >> 1, wx = wave & 1;
    const int quad = lane >> 4, l15 = lane & 15;
#pragma unroll
    for (int mi = 0; mi < 4; ++mi)
#pragma unroll
        for (int reg = 0; reg < 4; ++reg) {
            int r = row0 + wy * 64 + mi * 16 + quad * 4 + reg;
            if (r >= NROWS) continue;
#pragma unroll
            for (int ni = 0; ni < 4; ++ni) {
                int o = col0 + wx * 64 + ni * 16 + l15;
                x1[(size_t)r * DIM + o] =
                    x0[(size_t)r * DIM + o] + 2.f * (acc[mi][ni][reg] + pb[o]);
            }
        }
}

// ============================ fc1 GEMM + exact GELU -> bf16 ==============
__global__ __launch_bounds__(256) void k_fc1(const bf16* __restrict__ h,
                                             const bf16* __restrict__ w,
                                             const float* __restrict__ fb,
                                             bf16* __restrict__ m1) {
    floatx4 acc[4][4] = {};
    const int row0 = blockIdx.y * 128, col0 = blockIdx.x * 128;
    mgemm<DIM>(h, w, row0, col0, acc);
    const int lane = threadIdx.x & 63, wave = threadIdx.x >> 6;
    const int wy = wave >> 1, wx = wave & 1;
    const int quad = lane >> 4, l15 = lane & 15;
#pragma unroll
    for (int mi = 0; mi < 4; ++mi)
#pragma unroll
        for (int reg = 0; reg < 4; ++reg) {
            int r = row0 + wy * 64 + mi * 16 + quad * 4 + reg;
            if (r >= NROWS) continue;
#pragma unroll
            for (int ni = 0; ni < 4; ++ni) {
                int o = col0 + wx * 64 + ni * 16 + l15;
                float z = acc[mi][ni][reg] + fb[o];
                m1[(size_t)r * MLPH + o] =
                    (bf16)(0.5f * z * (1.f + erff(z * 0.70710678118654752f)));
            }
        }
}

// ============================ fc2 GEMM + scale + residual ================
__global__ __launch_bounds__(256) void k_fc2(const bf16* __restrict__ m1,
                                             const bf16* __restrict__ w,
                                             const float* __restrict__ fb,
                                             const float* __restrict__ scch,
                                             const float* __restrict__ x1,
                                             float* __restrict__ xout) {
    floatx4 acc[4][4] = {};
    const int row0 = blockIdx.y * 128, col0 = blockIdx.x * 128;
    mgemm<MLPH>(m1, w, row0, col0, acc);
    const int lane = threadIdx.x & 63, wave = threadIdx.x >> 6;
    const int wy = wave >> 1, wx = wave & 1;
    const int quad = lane >> 4, l15 = lane & 15;
#pragma unroll
    for (int mi = 0; mi < 4; ++mi)
#pragma unroll
        for (int reg = 0; reg < 4; ++reg) {
            int r = row0 + wy * 64 + mi * 16 + quad * 4 + reg;
            if (r >= NROWS) continue;
#pragma unroll
            for (int ni = 0; ni < 4; ++ni) {
                int o = col0 + wx * 64 + ni * 16 + l15;
                xout[(size_t)r * DIM + o] =
                    x1[(size_t)r * DIM + o] + 2.f * (acc[mi][ni][reg] + fb[o]) * scch[o];
            }
        }
}

// ============================ scores + softmax ===========================
__global__ __launch_bounds__(256) void k_score(const float* __restrict__ q,
                                               const float* __restrict__ kmat,
                                               float* __restrict__ att) {
    __shared__ float Ks[NSEQ][36];
    __shared__ float Qs[16][36];
    const int bh = blockIdx.y;
    const int y0 = blockIdx.x * 16;
    const size_t kb = (size_t)bh * (NSEQ * HD);
    for (int i = threadIdx.x; i < NSEQ * HD; i += 256) Ks[i >> 5][i & 31] = kmat[kb + i];
    for (int i = threadIdx.x; i < 16 * HD; i += 256) {
        int rr = i >> 5, dd = i & 31, yy = y0 + rr;
        Qs[rr][dd] = (yy < NSEQ) ? q[kb + (size_t)yy * HD + dd] : 0.f;
    }
    __syncthreads();
    const int tx = threadIdx.x & 15, ty = threadIdx.x >> 4;
    const int y = y0 + ty;
    if (y >= NSEQ) return;
    float qr[32];
#pragma unroll
    for (int wq = 0; wq < 8; ++wq) *(float4*)&qr[wq * 4] = *(const float4*)&Qs[ty][wq * 4];
    float sc[13];
    float mx = -1e30f;
#pragma unroll
    for (int m = 0; m < 13; ++m) {
        int x = tx + m * 16;
        float d = -1e30f;
        if (x < NSEQ) {
            const float4* kp = (const float4*)&Ks[x][0];
            float a = 0.f;
#pragma unroll
            for (int wq = 0; wq < 8; ++wq) {
                float4 kv = kp[wq];
                a = fmaf(qr[wq * 4 + 0], kv.x, a);
                a = fmaf(qr[wq * 4 + 1], kv.y, a);
                a = fmaf(qr[wq * 4 + 2], kv.z, a);
                a = fmaf(qr[wq * 4 + 3], kv.w, a);
            }
            d = a;
        }
        sc[m] = d;
        mx = fmaxf(mx, d);
    }
#pragma unroll
    for (int off = 8; off >= 1; off >>= 1) mx = fmaxf(mx, __shfl_xor(mx, off, 16));
    float ssum = 0.f;
#pragma unroll
    for (int m = 0; m < 13; ++m) {
        int x = tx + m * 16;
        float e = (x < NSEQ) ? __expf(sc[m] - mx) : 0.f;
        sc[m] = e;
        ssum += e;
    }
#pragma unroll
    for (int off = 8; off >= 1; off >>= 1) ssum += __shfl_xor(ssum, off, 16);
    const float rinv = 1.f / ssum;
    const size_t ab = (size_t)bh * NN2 + (size_t)y * NSEQ;
#pragma unroll
    for (int m = 0; m < 13; ++m) {
        int x = tx + m * 16;
        if (x < NSEQ) att[ab + x] = sc[m] * rinv;
    }
}

// ============================ channel moments of attn0 ===================
__global__ __launch_bounds__(256) void k_moments(const float* __restrict__ att,
                                                 float* __restrict__ stats) {
    float mu[12] = {};
    float pr[78] = {};
    const int stride = gridDim.x * 256;
    for (int p = blockIdx.x * 256 + threadIdx.x; p < NPIX; p += stride) {
        int b = p / NN2;
        int s = p - b * NN2;
        const float* base = att + (size_t)b * 12 * NN2 + s;
        float v[12];
#pragma unroll
        for (int i = 0; i < 12; ++i) v[i] = base[(size_t)i * NN2];
#pragma unroll
        for (int i = 0; i < 12; ++i) mu[i] += v[i];
#pragma unroll
        for (int i = 0; i < 12; ++i)
#pragma unroll
            for (int j = i; j < 12; ++j)
                pr[i * (23 - i) / 2 + j] += v[i] * v[j];
    }
#pragma unroll
    for (int s = 0; s < 12; ++s)
#pragma unroll
        for (int off = 32; off >= 1; off >>= 1) mu[s] += __shfl_xor(mu[s], off);
#pragma unroll
    for (int s = 0; s < 78; ++s)
#pragma unroll
        for (int off = 32; off >= 1; off >>= 1) pr[s] += __shfl_xor(pr[s], off);
    __shared__ float red[4][90];
    const int lane = threadIdx.x & 63, wid = threadIdx.x >> 6;
    if (lane == 0) {
#pragma unroll
        for (int s = 0; s < 12; ++s) red[wid][s] = mu[s];
#pragma unroll
        for (int s = 0; s < 78; ++s) red[wid][12 + s] = pr[s];
    }
    __syncthreads();
    const int t = threadIdx.x;
    if (t < 90) {
        float tot = red[0][t] + red[1][t] + red[2][t] + red[3][t];
        int addr;
        if (t < 12) addr = ST_MOMSUM + t;
        else {
            int tt = t - 12;
            int i = 0;
            while (tt >= 12 - i) { tt -= 12 - i; ++i; }
            addr = ST_MOMPROD + i * 12 + (i + tt);
        }
        atomicAdd(&stats[addr], tot);
    }
}

// ============================ finalize bn1 (analytic) ====================
__global__ __launch_bounds__(64) void k_fin1(const float* __restrict__ wexp,
                                             const float* __restrict__ g1,
                                             const float* __restrict__ b1,
                                             float* __restrict__ stats) {
    int o = threadIdx.x;
    if (o >= 36) return;
    const float invM = 1.f / (float)NPIX;
    float mu[12];
#pragma unroll
    for (int i = 0; i < 12; ++i) mu[i] = stats[ST_MOMSUM + i] * invM;
    float mean = 0.f;
#pragma unroll
    for (int i = 0; i < 12; ++i) mean += wexp[o * 12 + i] * mu[i];
    float e2 = 0.f;
    for (int i = 0; i < 12; ++i)
        for (int j = 0; j < 12; ++j) {
            int a = i < j ? i : j, bj = i < j ? j : i;
            e2 += wexp[o * 12 + i] * wexp[o * 12 + j] * stats[ST_MOMPROD + a * 12 + bj] * invM;
        }
    float var = e2 - mean * mean;
    float sc = g1[o] * rsqrtf(var + EPS);
    stats[ST_SC1 + o] = sc;
    stats[ST_SH1 + o] = b1[o] - mean * sc;
}

// ====== PASS A: recompute expand+bn1+relu6+dw, accumulate bn2 sums =======
__global__ __launch_bounds__(256) void k_sums2(const float* __restrict__ att,
                                               const float* __restrict__ wexp,
                                               const float* __restrict__ dww,
                                               const float* __restrict__ stats,
                                               float* __restrict__ statw) {
    __shared__ float a0s[12][256];
    __shared__ float b1s[36][256];
    __shared__ float wexps[432];
    __shared__ float dws[324];
    __shared__ float sc1s[36], sh1s[36];
    __shared__ float sS[4][36], sQ[4][36];
    const int b = blockIdx.z;
    const int oy0 = blockIdx.y * 14, ox0 = blockIdx.x * 14;
    const int tid = threadIdx.x;
    for (int i = tid; i < 432; i += 256) wexps[i] = wexp[i];
    for (int i = tid; i < 324; i += 256) dws[i] = dww[i];
    if (tid < 36) { sc1s[tid] = stats[ST_SC1 + tid]; sh1s[tid] = stats[ST_SH1 + tid]; }
    const int lx = tid & 15, ly = tid >> 4;
    const int gy = oy0 - 1 + ly, gx = ox0 - 1 + lx;
    const bool valid = (gy >= 0 && gy < NSEQ && gx >= 0 && gx < NSEQ);
#pragma unroll
    for (int i = 0; i < 12; ++i)
        a0s[i][tid] = valid ? att[(size_t)(b * 12 + i) * NN2 + (size_t)gy * NSEQ + gx] : 0.f;
    __syncthreads();
    float a0v[12];
#pragma unroll
    for (int i = 0; i < 12; ++i) a0v[i] = a0s[i][tid];
#pragma unroll 4
    for (int o = 0; o < 36; ++o) {
        float t = 0.f;
#pragma unroll
        for (int i = 0; i < 12; ++i) t = fmaf(wexps[o * 12 + i], a0v[i], t);
        t = fminf(fmaxf(fmaf(sc1s[o], t, sh1s[o]), 0.f), 6.f);
        b1s[o][tid] = valid ? t : 0.f;
    }
    __syncthreads();
    const bool inter = (ly >= 1 && ly <= 14 && lx >= 1 && lx <= 14 &&
                        gy < NSEQ && gx < NSEQ);
    const int base = inter ? ((ly - 1) * 16 + (lx - 1)) : 0;
    const int lane = tid & 63, wid = tid >> 6;
    for (int o = 0; o < 36; ++o) {
        float s = 0.f;
        if (inter) {
            const float* bp = &b1s[o][base];
#pragma unroll
            for (int dy = 0; dy < 3; ++dy)
#pragma unroll
                for (int dx = 0; dx < 3; ++dx)
                    s = fmaf(dws[o * 9 + dy * 3 + dx], bp[dy * 16 + dx], s);
        }
        float qv = s * s;
#pragma unroll
        for (int off = 32; off >= 1; off >>= 1) {
            s  += __shfl_xor(s, off);
            qv += __shfl_xor(qv, off);
        }
        if (lane == 0) { sS[wid][o] = s; sQ[wid][o] = qv; }
    }
    __syncthreads();
    if (tid < 72) {
        int o = (tid < 36) ? tid : (tid - 36);
        float tot = (tid < 36)
            ? (sS[0][o] + sS[1][o] + sS[2][o] + sS[3][o])
            : (sQ[0][o] + sQ[1][o] + sQ[2][o] + sQ[3][o]);
        int slot = (blockIdx.z * 225 + blockIdx.y * 15 + blockIdx.x) & 63;
        int addr = (tid < 36) ? (ST_S2 + slot * 36 + o)
                              : (ST_SS2 + slot * 36 + o);
        atomicAdd(&statw[addr], tot);
    }
}

__global__ __launch_bounds__(64) void k_fin2(const float* __restrict__ g2,
                                             const float* __restrict__ b2,
                                             float* __restrict__ stats) {
    int o = threadIdx.x;
    if (o >= 36) return;
    float S = 0.f, SS = 0.f;
    for (int sl = 0; sl < 64; ++sl) {
        S += stats[ST_S2 + sl * 36 + o];
        SS += stats[ST_SS2 + sl * 36 + o];
    }
    const float invM = 1.f / (float)NPIX;
    float m = S * invM, var = SS * invM - m * m;
    float sc = g2[o] * rsqrtf(var + EPS);
    stats[ST_SC2 + o] = sc;
    stats[ST_SH2 + o] = b2[o] - m * sc;
}

// ====== PASS B: recompute + bn2 + relu6 + project 36->12 -> a3 only ======
__global__ __launch_bounds__(256) void k_p3(const float* __restrict__ att,
                                            const float* __restrict__ wexp,
                                            const float* __restrict__ dww,
                                            const float* __restrict__ pw,
                                            const float* __restrict__ stats,
                                            float* __restrict__ datt) {
    __shared__ float a0s[12][256];
    __shared__ float b1s[36][256];
    __shared__ float wexps[432];
    __shared__ float dws[324];
    __shared__ float pws[432];
    __shared__ float sc1s[36], sh1s[36], sc2s[36], sh2s[36];
    const int b = blockIdx.z;
    const int oy0 = blockIdx.y * 14, ox0 = blockIdx.x * 14;
    const int tid = threadIdx.x;
    for (int i = tid; i < 432; i += 256) { wexps[i] = wexp[i]; pws[i] = pw[i]; }
    for (int i = tid; i < 324; i += 256) dws[i] = dww[i];
    if (tid < 36) {
        sc1s[tid] = stats[ST_SC1 + tid]; sh1s[tid] = stats[ST_SH1 + tid];
        sc2s[tid] = stats[ST_SC2 + tid]; sh2s[tid] = stats[ST_SH2 + tid];
    }
    const int lx = tid & 15, ly = tid >> 4;
    const int gy = oy0 - 1 + ly, gx = ox0 - 1 + lx;
    const bool valid = (gy >= 0 && gy < NSEQ && gx >= 0 && gx < NSEQ);
#pragma unroll
    for (int i = 0; i < 12; ++i)
        a0s[i][tid] = valid ? att[(size_t)(b * 12 + i) * NN2 + (size_t)gy * NSEQ + gx] : 0.f;
    __syncthreads();
    float a0v[12];
#pragma unroll
    for (int i = 0; i < 12; ++i) a0v[i] = a0s[i][tid];
#pragma unroll 4
    for (int o = 0; o < 36; ++o) {
        float t = 0.f;
#pragma unroll
        for (int i = 0; i < 12; ++i) t = fmaf(wexps[o * 12 + i], a0v[i], t);
        t = fminf(fmaxf(fmaf(sc1s[o], t, sh1s[o]), 0.f), 6.f);
        b1s[o][tid] = valid ? t : 0.f;
    }
    __syncthreads();
    if (ly < 1 || ly > 14 || lx < 1 || lx > 14 || gy >= NSEQ || gx >= NSEQ) return;
    const int base = (ly - 1) * 16 + (lx - 1);
    float a3v[12] = {};
#pragma unroll 4
    for (int o = 0; o < 36; ++o) {
        const float* bp = &b1s[o][base];
        float s = 0.f;
#pragma unroll
        for (int dy = 0; dy < 3; ++dy)
#pragma unroll
            for (int dx = 0; dx < 3; ++dx)
                s = fmaf(dws[o * 9 + dy * 3 + dx], bp[dy * 16 + dx], s);
        float t = fminf(fmaxf(fmaf(sc2s[o], s, sh2s[o]), 0.f), 6.f);
#pragma unroll
        for (int c = 0; c < 12; ++c) a3v[c] = fmaf(pws[c * 36 + o], t, a3v[c]);
    }
    const size_t pix = (size_t)gy * NSEQ + gx;
#pragma unroll
    for (int c = 0; c < 12; ++c)
        datt[(size_t)(b * 12 + c) * NN2 + pix] = a3v[c];
}

// ====== 5 sums over (a3, a0) =============================================
__global__ __launch_bounds__(256) void k_p3sums(const float* __restrict__ a3,
                                                const float* __restrict__ att0,
                                                float* __restrict__ stats) {
    float st[60] = {};
    const int stride = gridDim.x * 256;
    for (int p = blockIdx.x * 256 + threadIdx.x; p < NPIX; p += stride) {
        int b = p / NN2;
        int s = p - b * NN2;
        const float* a3b = a3 + (size_t)b * 12 * NN2 + s;
        const float* a0b = att0 + (size_t)b * 12 * NN2 + s;
#pragma unroll
        for (int c = 0; c < 12; ++c) {
            float x3 = a3b[(size_t)c * NN2];
            float x0 = a0b[(size_t)c * NN2];
            st[c]      += x3;
            st[12 + c] = fmaf(x3, x3, st[12 + c]);
            st[24 + c] += x0;
            st[36 + c] = fmaf(x0, x0, st[36 + c]);
            st[48 + c] = fmaf(x3, x0, st[48 + c]);
        }
    }
#pragma unroll
    for (int c = 0; c < 60; ++c)
#pragma unroll
        for (int off = 32; off >= 1; off >>= 1) st[c] += __shfl_xor(st[c], off);
    __shared__ float red[4][60];
    const int lane = threadIdx.x & 63, wid = threadIdx.x >> 6;
    if (lane == 0) {
#pragma unroll
        for (int c = 0; c < 60; ++c) red[wid][c] = st[c];
    }
    __syncthreads();
    if (threadIdx.x < 60) {
        float tot = red[0][threadIdx.x] + red[1][threadIdx.x] +
                    red[2][threadIdx.x] + red[3][threadIdx.x];
        int slot = blockIdx.x & 63;
        atomicAdd(&stats[ST_P3 + slot * 60 + threadIdx.x], tot);
    }
}

// ============ finalize bn3 + adapt_bn -> affine alpha/beta/gamma =========
__global__ __launch_bounds__(64) void k_fin3(const float* __restrict__ g3,
                                             const float* __restrict__ b3,
                                             const float* __restrict__ ag,
                                             const float* __restrict__ ab,
                                             float* __restrict__ stats) {
    int c = threadIdx.x;
    if (c >= 12) return;
    float S3 = 0.f, S3q = 0.f, S0 = 0.f, S0q = 0.f, S30 = 0.f;
    for (int sl = 0; sl < 64; ++sl) {
        const float* p = stats + ST_P3 + sl * 60;
        S3 += p[c]; S3q += p[12 + c]; S0 += p[24 + c]; S0q += p[36 + c]; S30 += p[48 + c];
    }
    const float M = (float)NPIX;
    float m3 = S3 / M, v3 = S3q / M - m3 * m3;
    float pp = g3[c] * rsqrtf(v3 + EPS);
    float qq = b3[c] - m3 * pp;
    float my = (pp * S3 + S0) / M + qq;
    float Syq = pp * pp * S3q + S0q + qq * qq * M + 2.f * pp * S30 + 2.f * pp * qq * S3 + 2.f * qq * S0;
    float vy = Syq / M - my * my;
    float rr = ag[c] * rsqrtf(vy + EPS);
    float ss = ab[c] - my * rr;
    stats[ST_ABG + c] = rr * pp;
    stats[ST_ABG + 12 + c] = rr;
    stats[ST_ABG + 24 + c] = rr * qq + ss;
}

// ====== final attn (in-place affine) + AV product -> bf16 outm ===========
__global__ __launch_bounds__(256) void k_p4(float* __restrict__ datt,
                                            const float* __restrict__ att0,
                                            const float* __restrict__ v,
                                            const float* __restrict__ stats,
                                            bf16* __restrict__ outm) {
    __shared__ float Vs[NSEQ][36];
    const int bh = blockIdx.y;
    const int b = bh / 12, hh = bh - b * 12;
    const int y0 = blockIdx.x * 16;
    const size_t vb = (size_t)bh * (NSEQ * HD);
    for (int i = threadIdx.x; i < NSEQ * HD; i += 256) Vs[i >> 5][i & 31] = v[vb + i];
    __syncthreads();
    const float alpha = stats[ST_ABG + hh];
    const float beta  = stats[ST_ABG + 12 + hh];
    const float gamma = stats[ST_ABG + 24 + hh];
    const int tx = threadIdx.x & 15, ty = threadIdx.x >> 4;
    const int y = y0 + ty;
    if (y >= NSEQ) return;
    const size_t ab = (size_t)bh * NN2 + (size_t)y * NSEQ;
    float acc[32] = {};
    for (int m = 0; m < 13; ++m) {
        int x = tx + m * 16;
        if (x < NSEQ) {
            float av = alpha * datt[ab + x] + beta * att0[ab + x] + gamma;
            datt[ab + x] = av;
            const float4* vp = (const float4*)&Vs[x][0];
#pragma unroll
            for (int w = 0; w < 8; ++w) {
                float4 vv = vp[w];
                acc[4 * w + 0] = fmaf(av, vv.x, acc[4 * w + 0]);
                acc[4 * w + 1] = fmaf(av, vv.y, acc[4 * w + 1]);
                acc[4 * w + 2] = fmaf(av, vv.z, acc[4 * w + 2]);
                acc[4 * w + 3] = fmaf(av, vv.w, acc[4 * w + 3]);
            }
        }
    }
#pragma unroll
    for (int d = 0; d < 32; ++d)
#pragma unroll
        for (int off = 8; off >= 1; off >>= 1)
            acc[d] += __shfl_xor(acc[d], off, 16);
    if (tx == 0) {
        bf16* op = outm + ((size_t)b * NSEQ + y) * DIM + hh * HD;
#pragma unroll
        for (int d = 0; d < 32; ++d) op[d] = (bf16)acc[d];
    }
}

// ========================================================================
extern "C" void kernel_launch(void* const* d_in, const int* in_sizes, int n_in,
                              void* d_out, int out_size, void* d_ws, size_t ws_size,
                              hipStream_t stream) {
    const float* x     = (const float*)d_in[0];
    const float* ln1g  = (const float*)d_in[1];
    const float* ln1b  = (const float*)d_in[2];
    const float* qkvw  = (const float*)d_in[3];
    const float* wexp  = (const float*)d_in[4];
    const float* bn1g  = (const float*)d_in[5];
    const float* bn1b  = (const float*)d_in[6];
    const float* dww   = (const float*)d_in[7];
    const float* bn2g  = (const float*)d_in[8];
    const float* bn2b  = (const float*)d_in[9];
    const float* prow  = (const float*)d_in[10];
    const float* bn3g  = (const float*)d_in[11];
    const float* bn3b  = (const float*)d_in[12];
    const float* abng  = (const float*)d_in[13];
    const float* abnb  = (const float*)d_in[14];
    const float* projw = (const float*)d_in[15];
    const float* projb = (const float*)d_in[16];
    const float* ln2g  = (const float*)d_in[17];
    const float* ln2b  = (const float*)d_in[18];
    const float* fc1w  = (const float*)d_in[19];
    const float* fc1b  = (const float*)d_in[20];
    const float* fc2w  = (const float*)d_in[21];
    const float* fc2b  = (const float*)d_in[22];
    const float* scch  = (const float*)d_in[23];

    if (ws_size < WS_FLOATS * sizeof(float)) return;   // need ~107 MB scratch

    float* W     = (float*)d_ws;
    bf16*  hb    = (bf16*)(W + O_HB);     // h, then outm, then h2 (sequential)
    float* q     = W + O_Q;
    float* kx    = W + O_K;
    float* v     = W + O_V;
    float* att0  = W + O_ATT0;
    float* x1    = W + O_X1;
    bf16*  m1    = (bf16*)(W + O_ATT0);   // alias: att0 dead after k_p4
    bf16*  wqkvb = (bf16*)(W + O_WQKV);
    bf16*  wprjb = (bf16*)(W + O_WPRJ);
    bf16*  wfc1b = (bf16*)(W + O_WFC1);
    bf16*  wfc2b = (bf16*)(W + O_WFC2);
    float* stats = W + O_STATS;

    float* xout = (float*)d_out;
    float* datt = xout + XSIZE;

    hipMemsetAsync(stats, 0, ST_TOTAL * sizeof(float), stream);
    k_cvt<<<dim3(288, 4), 256, 0, stream>>>(qkvw, projw, fc1w, fc2w,
                                            wqkvb, wprjb, wfc1b, wfc2b);
    k_ln<<<NROWS, 384, 0, stream>>>(x, ln1g, ln1b, hb);
    k_qkv<<<dim3(9, 50), 256, 0, stream>>>(hb, wqkvb, q, kx, v);
    k_score<<<dim3(13, 384), 256, 0, stream>>>(q, kx, att0);
    k_moments<<<512, 256, 0, stream>>>(att0, stats);
    k_fin1<<<1, 64, 0, stream>>>(wexp, bn1g, bn1b, stats);
    k_sums2<<<dim3(15, 15, 32), 256, 0, stream>>>(att0, wexp, dww, stats, stats);
    k_fin2<<<1, 64, 0, stream>>>(bn2g, bn2b, stats);
    k_p3<<<dim3(15, 15, 32), 256, 0, stream>>>(att0, wexp, dww, prow, stats, datt);
    k_p3sums<<<512, 256, 0, stream>>>(datt, att0, stats);
    k_fin3<<<1, 64, 0, stream>>>(bn3g, bn3b, abng, abnb, stats);
    k_p4<<<dim3(13, 384), 256, 0, stream>>>(datt, att0, v, stats, hb);
    k_proj<<<dim3(3, 50), 256, 0, stream>>>(hb, wprjb, projb, x, x1);
    k_ln<<<NROWS, 384, 0, stream>>>(x1, ln2g, ln2b, hb);
    k_fc1<<<dim3(12, 50), 256, 0, stream>>>(hb, wfc1b, fc1b, m1);
    k_fc2<<<dim3(3, 50), 256, 0, stream>>>(m1, wfc2b, fc2b, scch, x1, xout);
}

// Round 6
// 813.923 us; speedup vs baseline: 1.9221x; 1.1310x over previous
//
#include <hip/hip_runtime.h>
#include <math.h>

#define EPS   1e-5f
#define NSEQ  197
#define DIM   384
#define NH    12
#define HD    32
#define MLPH  1536
#define NN2   38809          // 197*197
#define NROWS 6304           // 32*197
#define NPIX  1241888        // 32*38809
#define XSIZE 2420736        // 32*197*384 — exact size of output 0
#define SQF   0.4204482076268572f   // 32^(-0.25)

typedef __bf16 bf16;
typedef __attribute__((ext_vector_type(8))) __bf16 bf16x8;
typedef __attribute__((ext_vector_type(4))) float floatx4;
typedef unsigned int u32;
typedef const __attribute__((address_space(1))) u32* gptr_t;
typedef __attribute__((address_space(3))) u32* lptr_t;

// ---- stats scratch layout (floats, inside ws) ----
#define ST_MOMSUM  0      // 12
#define ST_MOMPROD 16     // 144 (i<=j at i*12+j)
#define ST_SC1     160    // 36
#define ST_SH1     200    // 36
#define ST_S2      256    // 64*36
#define ST_SS2     2560   // 64*36
#define ST_SC2     4864   // 36
#define ST_SH2     4900   // 36
#define ST_P3      4992   // 64*60
#define ST_ABG     8832   // 36 (alpha,beta,gamma)
#define ST_TOTAL   8896

// ---- workspace offsets (float slots) ----  total ~107 MB
#define O_HB    0ull              // bf16 [6400][384]  (h, then outm, then h2)
#define O_Q     1228800ull        // fp32 [32*12][197][32]
#define O_K     3649536ull
#define O_V     6070272ull
#define O_ATT0  8491008ull        // fp32 14902656 floats; m1 (bf16) aliases
#define O_X1    23393664ull       // fp32 2420736
#define O_WQKV  25814400ull       // bf16 1152x384
#define O_WPRJ  26035584ull       // bf16 384x384
#define O_WFC1  26109312ull       // bf16 1536x384
#define O_WFC2  26404224ull       // bf16 384x1536
#define O_STATS 26699136ull
#define WS_FLOATS (O_STATS + ST_TOTAL)

// ---- bf16x2 pack/unpack (truncation — identical in both DLA passes) ----
__device__ __forceinline__ u32 pack2(float a, float b) {
    u32 ua = __builtin_bit_cast(u32, a);
    u32 ub = __builtin_bit_cast(u32, b);
    return (ua >> 16) | (ub & 0xffff0000u);
}
__device__ __forceinline__ float unpk_lo(u32 w) { return __builtin_bit_cast(float, w << 16); }
__device__ __forceinline__ float unpk_hi(u32 w) { return __builtin_bit_cast(float, w & 0xffff0000u); }

// ============================ weight fp32 -> bf16 ========================
__global__ __launch_bounds__(256) void k_cvt(const float* __restrict__ s0,
                                             const float* __restrict__ s1,
                                             const float* __restrict__ s2,
                                             const float* __restrict__ s3,
                                             bf16* __restrict__ d0,
                                             bf16* __restrict__ d1,
                                             bf16* __restrict__ d2,
                                             bf16* __restrict__ d3) {
    const int w = blockIdx.y;
    const float* s = (w == 0) ? s0 : (w == 1) ? s1 : (w == 2) ? s2 : s3;
    bf16* d = (w == 0) ? d0 : (w == 1) ? d1 : (w == 2) ? d2 : d3;
    const int n = (w == 0) ? 442368 : (w == 1) ? 147456 : 589824;
    for (int i = blockIdx.x * 256 + threadIdx.x; i < n; i += gridDim.x * 256)
        d[i] = (bf16)s[i];
}

// ============================ LayerNorm (x*0.5) -> bf16 ==================
__global__ __launch_bounds__(384) void k_ln(const float* __restrict__ xin,
                                            const float* __restrict__ g,
                                            const float* __restrict__ bb,
                                            bf16* __restrict__ hout) {
    const int r = blockIdx.x;
    const int t = threadIdx.x;
    float v = xin[(size_t)r * DIM + t] * 0.5f;
    float s = v, sq = v * v;
#pragma unroll
    for (int off = 32; off >= 1; off >>= 1) {
        s  += __shfl_xor(s, off);
        sq += __shfl_xor(sq, off);
    }
    __shared__ float ls[6], lq[6];
    __shared__ float mv[2];
    const int wid = t >> 6;
    if ((t & 63) == 0) { ls[wid] = s; lq[wid] = sq; }
    __syncthreads();
    if (t == 0) {
        float S = 0.f, Q = 0.f;
        for (int i = 0; i < 6; ++i) { S += ls[i]; Q += lq[i]; }
        float m = S / (float)DIM;
        mv[0] = m;
        mv[1] = rsqrtf(Q / (float)DIM - m * m + EPS);
    }
    __syncthreads();
    hout[(size_t)r * DIM + t] = (bf16)((v - mv[0]) * mv[1] * g[t] + bb[t]);
}

// =============== 128x128 bf16 MFMA GEMM core: C = A[M][K] @ B[N][K]^T ====
template <int KDIM>
__device__ __forceinline__ void mgemm(const bf16* __restrict__ A,
                                      const bf16* __restrict__ B,
                                      int row0, int col0,
                                      floatx4 (&acc)[4][4]) {
    __shared__ bf16 As[128 * 32];
    __shared__ bf16 Bs[128 * 32];
    const int tid = threadIdx.x;
    const int lane = tid & 63, wave = tid >> 6;
    const int wy = wave >> 1, wx = wave & 1;
    const int quad = lane >> 4, l15 = lane & 15;
    for (int k0 = 0; k0 < KDIM; k0 += 32) {
#pragma unroll
        for (int i = 0; i < 2; ++i) {
            const int e = (i * 256 + tid) * 8;           // bf16 elem offset in tile
            const int r = e >> 5, kk = e & 31;
            __builtin_amdgcn_global_load_lds(
                (gptr_t)(A + (size_t)(row0 + r) * KDIM + k0 + kk),
                (lptr_t)(As + e), 16, 0, 0);
            __builtin_amdgcn_global_load_lds(
                (gptr_t)(B + (size_t)(col0 + r) * KDIM + k0 + kk),
                (lptr_t)(Bs + e), 16, 0, 0);
        }
        __syncthreads();
        bf16x8 af[4], bfr[4];
#pragma unroll
        for (int mi = 0; mi < 4; ++mi)
            af[mi] = *(const bf16x8*)&As[(wy * 64 + mi * 16 + l15) * 32 + quad * 8];
#pragma unroll
        for (int ni = 0; ni < 4; ++ni)
            bfr[ni] = *(const bf16x8*)&Bs[(wx * 64 + ni * 16 + l15) * 32 + quad * 8];
#pragma unroll
        for (int mi = 0; mi < 4; ++mi)
#pragma unroll
            for (int ni = 0; ni < 4; ++ni)
                acc[mi][ni] = __builtin_amdgcn_mfma_f32_16x16x32_bf16(
                    af[mi], bfr[ni], acc[mi][ni], 0, 0, 0);
        __syncthreads();
    }
}

// ============================ QKV GEMM + scatter =========================
__global__ __launch_bounds__(256) void k_qkv(const bf16* __restrict__ h,
                                             const bf16* __restrict__ w,
                                             float* __restrict__ q,
                                             float* __restrict__ kx,
                                             float* __restrict__ v) {
    floatx4 acc[4][4] = {};
    const int row0 = blockIdx.y * 128, col0 = blockIdx.x * 128;
    mgemm<DIM>(h, w, row0, col0, acc);
    const int lane = threadIdx.x & 63, wave = threadIdx.x >> 6;
    const int wy = wave >> 1, wx = wave & 1;
    const int quad = lane >> 4, l15 = lane & 15;
#pragma unroll
    for (int mi = 0; mi < 4; ++mi)
#pragma unroll
        for (int reg = 0; reg < 4; ++reg) {
            int r = row0 + wy * 64 + mi * 16 + quad * 4 + reg;
            if (r >= NROWS) continue;
            int b = r / NSEQ, n = r - b * NSEQ;
#pragma unroll
            for (int ni = 0; ni < 4; ++ni) {
                int o = col0 + wx * 64 + ni * 16 + l15;
                int sec = o / DIM;
                int hh = (o >> 5) % NH;
                int dd = o & 31;
                float val = acc[mi][ni][reg];
                float* dst = (sec == 0) ? q : ((sec == 1) ? kx : v);
                if (sec < 2) val *= SQF;
                dst[((size_t)(b * NH + hh) * NSEQ + n) * HD + dd] = val;
            }
        }
}

// ============================ proj GEMM + residual =======================
__global__ __launch_bounds__(256) void k_proj(const bf16* __restrict__ outm,
                                              const bf16* __restrict__ w,
                                              const float* __restrict__ pb,
                                              const float* __restrict__ x0,
                                              float* __restrict__ x1) {
    floatx4 acc[4][4] = {};
    const int row0 = blockIdx.y * 128, col0 = blockIdx.x * 128;
    mgemm<DIM>(outm, w, row0, col0, acc);
    const int lane = threadIdx.x & 63, wave = threadIdx.x >> 6;
    const int wy = wave >> 1, wx = wave & 1;
    const int quad = lane >> 4, l15 = lane & 15;
#pragma unroll
    for (int mi = 0; mi < 4; ++mi)
#pragma unroll
        for (int reg = 0; reg < 4; ++reg) {
            int r = row0 + wy * 64 + mi * 16 + quad * 4 + reg;
            if (r >= NROWS) continue;
#pragma unroll
            for (int ni = 0; ni < 4; ++ni) {
                int o = col0 + wx * 64 + ni * 16 + l15;
                x1[(size_t)r * DIM + o] =
                    x0[(size_t)r * DIM + o] + 2.f * (acc[mi][ni][reg] + pb[o]);
            }
        }
}

// ============================ fc1 GEMM + exact GELU -> bf16 ==============
__global__ __launch_bounds__(256) void k_fc1(const bf16* __restrict__ h,
                                             const bf16* __restrict__ w,
                                             const float* __restrict__ fb,
                                             bf16* __restrict__ m1) {
    floatx4 acc[4][4] = {};
    const int row0 = blockIdx.y * 128, col0 = blockIdx.x * 128;
    mgemm<DIM>(h, w, row0, col0, acc);
    const int lane = threadIdx.x & 63, wave = threadIdx.x >> 6;
    const int wy = wave >> 1, wx = wave & 1;
    const int quad = lane >> 4, l15 = lane & 15;
#pragma unroll
    for (int mi = 0; mi < 4; ++mi)
#pragma unroll
        for (int reg = 0; reg < 4; ++reg) {
            int r = row0 + wy * 64 + mi * 16 + quad * 4 + reg;
            if (r >= NROWS) continue;
#pragma unroll
            for (int ni = 0; ni < 4; ++ni) {
                int o = col0 + wx * 64 + ni * 16 + l15;
                float z = acc[mi][ni][reg] + fb[o];
                m1[(size_t)r * MLPH + o] =
                    (bf16)(0.5f * z * (1.f + erff(z * 0.70710678118654752f)));
            }
        }
}

// ============================ fc2 GEMM + scale + residual ================
__global__ __launch_bounds__(256) void k_fc2(const bf16* __restrict__ m1,
                                             const bf16* __restrict__ w,
                                             const float* __restrict__ fb,
                                             const float* __restrict__ scch,
                                             const float* __restrict__ x1,
                                             float* __restrict__ xout) {
    floatx4 acc[4][4] = {};
    const int row0 = blockIdx.y * 128, col0 = blockIdx.x * 128;
    mgemm<MLPH>(m1, w, row0, col0, acc);
    const int lane = threadIdx.x & 63, wave = threadIdx.x >> 6;
    const int wy = wave >> 1, wx = wave & 1;
    const int quad = lane >> 4, l15 = lane & 15;
#pragma unroll
    for (int mi = 0; mi < 4; ++mi)
#pragma unroll
        for (int reg = 0; reg < 4; ++reg) {
            int r = row0 + wy * 64 + mi * 16 + quad * 4 + reg;
            if (r >= NROWS) continue;
#pragma unroll
            for (int ni = 0; ni < 4; ++ni) {
                int o = col0 + wx * 64 + ni * 16 + l15;
                xout[(size_t)r * DIM + o] =
                    x1[(size_t)r * DIM + o] + 2.f * (acc[mi][ni][reg] + fb[o]) * scch[o];
            }
        }
}

// ============================ scores + softmax ===========================
__global__ __launch_bounds__(256) void k_score(const float* __restrict__ q,
                                               const float* __restrict__ kmat,
                                               float* __restrict__ att) {
    __shared__ float Ks[NSEQ][36];
    __shared__ float Qs[16][36];
    const int bh = blockIdx.y;
    const int y0 = blockIdx.x * 16;
    const size_t kb = (size_t)bh * (NSEQ * HD);
    for (int i = threadIdx.x; i < NSEQ * HD; i += 256) Ks[i >> 5][i & 31] = kmat[kb + i];
    for (int i = threadIdx.x; i < 16 * HD; i += 256) {
        int rr = i >> 5, dd = i & 31, yy = y0 + rr;
        Qs[rr][dd] = (yy < NSEQ) ? q[kb + (size_t)yy * HD + dd] : 0.f;
    }
    __syncthreads();
    const int tx = threadIdx.x & 15, ty = threadIdx.x >> 4;
    const int y = y0 + ty;
    if (y >= NSEQ) return;
    float qr[32];
#pragma unroll
    for (int wq = 0; wq < 8; ++wq) *(float4*)&qr[wq * 4] = *(const float4*)&Qs[ty][wq * 4];
    float sc[13];
    float mx = -1e30f;
#pragma unroll
    for (int m = 0; m < 13; ++m) {
        int x = tx + m * 16;
        float d = -1e30f;
        if (x < NSEQ) {
            const float4* kp = (const float4*)&Ks[x][0];
            float a = 0.f;
#pragma unroll
            for (int wq = 0; wq < 8; ++wq) {
                float4 kv = kp[wq];
                a = fmaf(qr[wq * 4 + 0], kv.x, a);
                a = fmaf(qr[wq * 4 + 1], kv.y, a);
                a = fmaf(qr[wq * 4 + 2], kv.z, a);
                a = fmaf(qr[wq * 4 + 3], kv.w, a);
            }
            d = a;
        }
        sc[m] = d;
        mx = fmaxf(mx, d);
    }
#pragma unroll
    for (int off = 8; off >= 1; off >>= 1) mx = fmaxf(mx, __shfl_xor(mx, off, 16));
    float ssum = 0.f;
#pragma unroll
    for (int m = 0; m < 13; ++m) {
        int x = tx + m * 16;
        float e = (x < NSEQ) ? __expf(sc[m] - mx) : 0.f;
        sc[m] = e;
        ssum += e;
    }
#pragma unroll
    for (int off = 8; off >= 1; off >>= 1) ssum += __shfl_xor(ssum, off, 16);
    const float rinv = 1.f / ssum;
    const size_t ab = (size_t)bh * NN2 + (size_t)y * NSEQ;
#pragma unroll
    for (int m = 0; m < 13; ++m) {
        int x = tx + m * 16;
        if (x < NSEQ) att[ab + x] = sc[m] * rinv;
    }
}

// ============================ channel moments of attn0 ===================
__global__ __launch_bounds__(256) void k_moments(const float* __restrict__ att,
                                                 float* __restrict__ stats) {
    float mu[12] = {};
    float pr[78] = {};
    const int stride = gridDim.x * 256;
    for (int p = blockIdx.x * 256 + threadIdx.x; p < NPIX; p += stride) {
        int b = p / NN2;
        int s = p - b * NN2;
        const float* base = att + (size_t)b * 12 * NN2 + s;
        float v[12];
#pragma unroll
        for (int i = 0; i < 12; ++i) v[i] = base[(size_t)i * NN2];
#pragma unroll
        for (int i = 0; i < 12; ++i) mu[i] += v[i];
#pragma unroll
        for (int i = 0; i < 12; ++i)
#pragma unroll
            for (int j = i; j < 12; ++j)
                pr[i * (23 - i) / 2 + j] += v[i] * v[j];
    }
#pragma unroll
    for (int s = 0; s < 12; ++s)
#pragma unroll
        for (int off = 32; off >= 1; off >>= 1) mu[s] += __shfl_xor(mu[s], off);
#pragma unroll
    for (int s = 0; s < 78; ++s)
#pragma unroll
        for (int off = 32; off >= 1; off >>= 1) pr[s] += __shfl_xor(pr[s], off);
    __shared__ float red[4][90];
    const int lane = threadIdx.x & 63, wid = threadIdx.x >> 6;
    if (lane == 0) {
#pragma unroll
        for (int s = 0; s < 12; ++s) red[wid][s] = mu[s];
#pragma unroll
        for (int s = 0; s < 78; ++s) red[wid][12 + s] = pr[s];
    }
    __syncthreads();
    const int t = threadIdx.x;
    if (t < 90) {
        float tot = red[0][t] + red[1][t] + red[2][t] + red[3][t];
        int addr;
        if (t < 12) addr = ST_MOMSUM + t;
        else {
            int tt = t - 12;
            int i = 0;
            while (tt >= 12 - i) { tt -= 12 - i; ++i; }
            addr = ST_MOMPROD + i * 12 + (i + tt);
        }
        atomicAdd(&stats[addr], tot);
    }
}

// ============================ finalize bn1 (analytic) ====================
__global__ __launch_bounds__(64) void k_fin1(const float* __restrict__ wexp,
                                             const float* __restrict__ g1,
                                             const float* __restrict__ b1,
                                             float* __restrict__ stats) {
    int o = threadIdx.x;
    if (o >= 36) return;
    const float invM = 1.f / (float)NPIX;
    float mu[12];
#pragma unroll
    for (int i = 0; i < 12; ++i) mu[i] = stats[ST_MOMSUM + i] * invM;
    float mean = 0.f;
#pragma unroll
    for (int i = 0; i < 12; ++i) mean += wexp[o * 12 + i] * mu[i];
    float e2 = 0.f;
    for (int i = 0; i < 12; ++i)
        for (int j = 0; j < 12; ++j) {
            int a = i < j ? i : j, bj = i < j ? j : i;
            e2 += wexp[o * 12 + i] * wexp[o * 12 + j] * stats[ST_MOMPROD + a * 12 + bj] * invM;
        }
    float var = e2 - mean * mean;
    float sc = g1[o] * rsqrtf(var + EPS);
    stats[ST_SC1 + o] = sc;
    stats[ST_SH1 + o] = b1[o] - mean * sc;
}

// ====== PASS A: recompute expand+bn1+relu6+dw (bf16x2-packed b1),  =======
// ====== accumulate bn2 sums via quad-reduce + LDS 2-stage          =======
__global__ __launch_bounds__(256) void k_sums2(const float* __restrict__ att,
                                               const float* __restrict__ wexp,
                                               const float* __restrict__ dww,
                                               const float* __restrict__ stats,
                                               float* __restrict__ statw) {
    __shared__ float a0s[12][256];
    __shared__ u32  b1p[18][256];
    __shared__ float wexps[432];
    __shared__ float dws[324];
    __shared__ float sc1s[36], sh1s[36];
    __shared__ float red[64][73];     // [leader][72 partials], 73 kills bank conflicts
    const int b = blockIdx.z;
    const int oy0 = blockIdx.y * 14, ox0 = blockIdx.x * 14;
    const int tid = threadIdx.x;
    for (int i = tid; i < 432; i += 256) wexps[i] = wexp[i];
    for (int i = tid; i < 324; i += 256) dws[i] = dww[i];
    if (tid < 36) { sc1s[tid] = stats[ST_SC1 + tid]; sh1s[tid] = stats[ST_SH1 + tid]; }
    const int lx = tid & 15, ly = tid >> 4;
    const int gy = oy0 - 1 + ly, gx = ox0 - 1 + lx;
    const bool valid = (gy >= 0 && gy < NSEQ && gx >= 0 && gx < NSEQ);
#pragma unroll
    for (int i = 0; i < 12; ++i)
        a0s[i][tid] = valid ? att[(size_t)(b * 12 + i) * NN2 + (size_t)gy * NSEQ + gx] : 0.f;
    __syncthreads();
    float a0v[12];
#pragma unroll
    for (int i = 0; i < 12; ++i) a0v[i] = a0s[i][tid];
#pragma unroll 3
    for (int pp = 0; pp < 18; ++pp) {
        float t0 = 0.f, t1 = 0.f;
#pragma unroll
        for (int i = 0; i < 12; ++i) {
            t0 = fmaf(wexps[(2 * pp) * 12 + i], a0v[i], t0);
            t1 = fmaf(wexps[(2 * pp + 1) * 12 + i], a0v[i], t1);
        }
        t0 = fminf(fmaxf(fmaf(sc1s[2 * pp], t0, sh1s[2 * pp]), 0.f), 6.f);
        t1 = fminf(fmaxf(fmaf(sc1s[2 * pp + 1], t1, sh1s[2 * pp + 1]), 0.f), 6.f);
        if (!valid) { t0 = 0.f; t1 = 0.f; }
        b1p[pp][tid] = pack2(t0, t1);
    }
    __syncthreads();
    const bool inter = (ly >= 1 && ly <= 14 && lx >= 1 && lx <= 14 &&
                        gy < NSEQ && gx < NSEQ);
    const int base = inter ? ((ly - 1) * 16 + (lx - 1)) : 0;
    const int leader = tid >> 2;
#pragma unroll 3
    for (int pp = 0; pp < 18; ++pp) {
        float s0 = 0.f, s1 = 0.f;
        if (inter) {
            const u32* bp = &b1p[pp][base];
#pragma unroll
            for (int dy = 0; dy < 3; ++dy)
#pragma unroll
                for (int dx = 0; dx < 3; ++dx) {
                    u32 w = bp[dy * 16 + dx];
                    s0 = fmaf(dws[(2 * pp) * 9 + dy * 3 + dx], unpk_lo(w), s0);
                    s1 = fmaf(dws[(2 * pp + 1) * 9 + dy * 3 + dx], unpk_hi(w), s1);
                }
        }
        float q0 = s0 * s0, q1 = s1 * s1;
        s0 += __shfl_xor(s0, 1); s0 += __shfl_xor(s0, 2);
        s1 += __shfl_xor(s1, 1); s1 += __shfl_xor(s1, 2);
        q0 += __shfl_xor(q0, 1); q0 += __shfl_xor(q0, 2);
        q1 += __shfl_xor(q1, 1); q1 += __shfl_xor(q1, 2);
        if ((tid & 3) == 0) {
            red[leader][pp * 4 + 0] = s0;
            red[leader][pp * 4 + 1] = s1;
            red[leader][pp * 4 + 2] = q0;
            red[leader][pp * 4 + 3] = q1;
        }
    }
    __syncthreads();
    if (tid < 72) {
        float tot = 0.f;
        for (int l = 0; l < 64; ++l) tot += red[l][tid];
        int pp = tid >> 2, j = tid & 3;
        int c = 2 * pp + (j & 1);
        int isq = j >> 1;
        int slot = (blockIdx.z * 225 + blockIdx.y * 15 + blockIdx.x) & 63;
        atomicAdd(&statw[(isq ? ST_SS2 : ST_S2) + slot * 36 + c], tot);
    }
}

__global__ __launch_bounds__(64) void k_fin2(const float* __restrict__ g2,
                                             const float* __restrict__ b2,
                                             float* __restrict__ stats) {
    int o = threadIdx.x;
    if (o >= 36) return;
    float S = 0.f, SS = 0.f;
    for (int sl = 0; sl < 64; ++sl) {
        S += stats[ST_S2 + sl * 36 + o];
        SS += stats[ST_SS2 + sl * 36 + o];
    }
    const float invM = 1.f / (float)NPIX;
    float m = S * invM, var = SS * invM - m * m;
    float sc = g2[o] * rsqrtf(var + EPS);
    stats[ST_SC2 + o] = sc;
    stats[ST_SH2 + o] = b2[o] - m * sc;
}

// ====== PASS B: recompute (packed b1) + bn2 + relu6 + project -> a3 ======
__global__ __launch_bounds__(256) void k_p3(const float* __restrict__ att,
                                            const float* __restrict__ wexp,
                                            const float* __restrict__ dww,
                                            const float* __restrict__ pw,
                                            const float* __restrict__ stats,
                                            float* __restrict__ datt) {
    __shared__ float a0s[12][256];
    __shared__ u32  b1p[18][256];
    __shared__ float wexps[432];
    __shared__ float dws[324];
    __shared__ float pws[432];
    __shared__ float sc1s[36], sh1s[36], sc2s[36], sh2s[36];
    const int b = blockIdx.z;
    const int oy0 = blockIdx.y * 14, ox0 = blockIdx.x * 14;
    const int tid = threadIdx.x;
    for (int i = tid; i < 432; i += 256) { wexps[i] = wexp[i]; pws[i] = pw[i]; }
    for (int i = tid; i < 324; i += 256) dws[i] = dww[i];
    if (tid < 36) {
        sc1s[tid] = stats[ST_SC1 + tid]; sh1s[tid] = stats[ST_SH1 + tid];
        sc2s[tid] = stats[ST_SC2 + tid]; sh2s[tid] = stats[ST_SH2 + tid];
    }
    const int lx = tid & 15, ly = tid >> 4;
    const int gy = oy0 - 1 + ly, gx = ox0 - 1 + lx;
    const bool valid = (gy >= 0 && gy < NSEQ && gx >= 0 && gx < NSEQ);
#pragma unroll
    for (int i = 0; i < 12; ++i)
        a0s[i][tid] = valid ? att[(size_t)(b * 12 + i) * NN2 + (size_t)gy * NSEQ + gx] : 0.f;
    __syncthreads();
    float a0v[12];
#pragma unroll
    for (int i = 0; i < 12; ++i) a0v[i] = a0s[i][tid];
#pragma unroll 3
    for (int pp = 0; pp < 18; ++pp) {
        float t0 = 0.f, t1 = 0.f;
#pragma unroll
        for (int i = 0; i < 12; ++i) {
            t0 = fmaf(wexps[(2 * pp) * 12 + i], a0v[i], t0);
            t1 = fmaf(wexps[(2 * pp + 1) * 12 + i], a0v[i], t1);
        }
        t0 = fminf(fmaxf(fmaf(sc1s[2 * pp], t0, sh1s[2 * pp]), 0.f), 6.f);
        t1 = fminf(fmaxf(fmaf(sc1s[2 * pp + 1], t1, sh1s[2 * pp + 1]), 0.f), 6.f);
        if (!valid) { t0 = 0.f; t1 = 0.f; }
        b1p[pp][tid] = pack2(t0, t1);
    }
    __syncthreads();
    if (ly < 1 || ly > 14 || lx < 1 || lx > 14 || gy >= NSEQ || gx >= NSEQ) return;
    const int base = (ly - 1) * 16 + (lx - 1);
    float a3v[12] = {};
#pragma unroll 3
    for (int pp = 0; pp < 18; ++pp) {
        const u32* bp = &b1p[pp][base];
        float s0 = 0.f, s1 = 0.f;
#pragma unroll
        for (int dy = 0; dy < 3; ++dy)
#pragma unroll
            for (int dx = 0; dx < 3; ++dx) {
                u32 w = bp[dy * 16 + dx];
                s0 = fmaf(dws[(2 * pp) * 9 + dy * 3 + dx], unpk_lo(w), s0);
                s1 = fmaf(dws[(2 * pp + 1) * 9 + dy * 3 + dx], unpk_hi(w), s1);
            }
        float u0 = fminf(fmaxf(fmaf(sc2s[2 * pp], s0, sh2s[2 * pp]), 0.f), 6.f);
        float u1 = fminf(fmaxf(fmaf(sc2s[2 * pp + 1], s1, sh2s[2 * pp + 1]), 0.f), 6.f);
#pragma unroll
        for (int c = 0; c < 12; ++c)
            a3v[c] = fmaf(pws[c * 36 + 2 * pp], u0,
                     fmaf(pws[c * 36 + 2 * pp + 1], u1, a3v[c]));
    }
    const size_t pix = (size_t)gy * NSEQ + gx;
#pragma unroll
    for (int c = 0; c < 12; ++c)
        datt[(size_t)(b * 12 + c) * NN2 + pix] = a3v[c];
}

// ====== 5 sums over (a3, a0) =============================================
__global__ __launch_bounds__(256) void k_p3sums(const float* __restrict__ a3,
                                                const float* __restrict__ att0,
                                                float* __restrict__ stats) {
    float st[60] = {};
    const int stride = gridDim.x * 256;
    for (int p = blockIdx.x * 256 + threadIdx.x; p < NPIX; p += stride) {
        int b = p / NN2;
        int s = p - b * NN2;
        const float* a3b = a3 + (size_t)b * 12 * NN2 + s;
        const float* a0b = att0 + (size_t)b * 12 * NN2 + s;
#pragma unroll
        for (int c = 0; c < 12; ++c) {
            float x3 = a3b[(size_t)c * NN2];
            float x0 = a0b[(size_t)c * NN2];
            st[c]      += x3;
            st[12 + c] = fmaf(x3, x3, st[12 + c]);
            st[24 + c] += x0;
            st[36 + c] = fmaf(x0, x0, st[36 + c]);
            st[48 + c] = fmaf(x3, x0, st[48 + c]);
        }
    }
#pragma unroll
    for (int c = 0; c < 60; ++c)
#pragma unroll
        for (int off = 32; off >= 1; off >>= 1) st[c] += __shfl_xor(st[c], off);
    __shared__ float red[4][60];
    const int lane = threadIdx.x & 63, wid = threadIdx.x >> 6;
    if (lane == 0) {
#pragma unroll
        for (int c = 0; c < 60; ++c) red[wid][c] = st[c];
    }
    __syncthreads();
    if (threadIdx.x < 60) {
        float tot = red[0][threadIdx.x] + red[1][threadIdx.x] +
                    red[2][threadIdx.x] + red[3][threadIdx.x];
        int slot = blockIdx.x & 63;
        atomicAdd(&stats[ST_P3 + slot * 60 + threadIdx.x], tot);
    }
}

// ============ finalize bn3 + adapt_bn -> affine alpha/beta/gamma =========
__global__ __launch_bounds__(64) void k_fin3(const float* __restrict__ g3,
                                             const float* __restrict__ b3,
                                             const float* __restrict__ ag,
                                             const float* __restrict__ ab,
                                             float* __restrict__ stats) {
    int c = threadIdx.x;
    if (c >= 12) return;
    float S3 = 0.f, S3q = 0.f, S0 = 0.f, S0q = 0.f, S30 = 0.f;
    for (int sl = 0; sl < 64; ++sl) {
        const float* p = stats + ST_P3 + sl * 60;
        S3 += p[c]; S3q += p[12 + c]; S0 += p[24 + c]; S0q += p[36 + c]; S30 += p[48 + c];
    }
    const float M = (float)NPIX;
    float m3 = S3 / M, v3 = S3q / M - m3 * m3;
    float pp = g3[c] * rsqrtf(v3 + EPS);
    float qq = b3[c] - m3 * pp;
    float my = (pp * S3 + S0) / M + qq;
    float Syq = pp * pp * S3q + S0q + qq * qq * M + 2.f * pp * S30 + 2.f * pp * qq * S3 + 2.f * qq * S0;
    float vy = Syq / M - my * my;
    float rr = ag[c] * rsqrtf(vy + EPS);
    float ss = ab[c] - my * rr;
    stats[ST_ABG + c] = rr * pp;
    stats[ST_ABG + 12 + c] = rr;
    stats[ST_ABG + 24 + c] = rr * qq + ss;
}

// ====== final attn (in-place affine) + AV product -> bf16 outm ===========
__global__ __launch_bounds__(256) void k_p4(float* __restrict__ datt,
                                            const float* __restrict__ att0,
                                            const float* __restrict__ v,
                                            const float* __restrict__ stats,
                                            bf16* __restrict__ outm) {
    __shared__ float Vs[NSEQ][36];
    const int bh = blockIdx.y;
    const int b = bh / 12, hh = bh - b * 12;
    const int y0 = blockIdx.x * 16;
    const size_t vb = (size_t)bh * (NSEQ * HD);
    for (int i = threadIdx.x; i < NSEQ * HD; i += 256) Vs[i >> 5][i & 31] = v[vb + i];
    __syncthreads();
    const float alpha = stats[ST_ABG + hh];
    const float beta  = stats[ST_ABG + 12 + hh];
    const float gamma = stats[ST_ABG + 24 + hh];
    const int tx = threadIdx.x & 15, ty = threadIdx.x >> 4;
    const int y = y0 + ty;
    if (y >= NSEQ) return;
    const size_t ab = (size_t)bh * NN2 + (size_t)y * NSEQ;
    float acc[32] = {};
    for (int m = 0; m < 13; ++m) {
        int x = tx + m * 16;
        if (x < NSEQ) {
            float av = alpha * datt[ab + x] + beta * att0[ab + x] + gamma;
            datt[ab + x] = av;
            const float4* vp = (const float4*)&Vs[x][0];
#pragma unroll
            for (int w = 0; w < 8; ++w) {
                float4 vv = vp[w];
                acc[4 * w + 0] = fmaf(av, vv.x, acc[4 * w + 0]);
                acc[4 * w + 1] = fmaf(av, vv.y, acc[4 * w + 1]);
                acc[4 * w + 2] = fmaf(av, vv.z, acc[4 * w + 2]);
                acc[4 * w + 3] = fmaf(av, vv.w, acc[4 * w + 3]);
            }
        }
    }
#pragma unroll
    for (int d = 0; d < 32; ++d)
#pragma unroll
        for (int off = 8; off >= 1; off >>= 1)
            acc[d] += __shfl_xor(acc[d], off, 16);
    if (tx == 0) {
        bf16* op = outm + ((size_t)b * NSEQ + y) * DIM + hh * HD;
#pragma unroll
        for (int d = 0; d < 32; ++d) op[d] = (bf16)acc[d];
    }
}

// ========================================================================
extern "C" void kernel_launch(void* const* d_in, const int* in_sizes, int n_in,
                              void* d_out, int out_size, void* d_ws, size_t ws_size,
                              hipStream_t stream) {
    const float* x     = (const float*)d_in[0];
    const float* ln1g  = (const float*)d_in[1];
    const float* ln1b  = (const float*)d_in[2];
    const float* qkvw  = (const float*)d_in[3];
    const float* wexp  = (const float*)d_in[4];
    const float* bn1g  = (const float*)d_in[5];
    const float* bn1b  = (const float*)d_in[6];
    const float* dww   = (const float*)d_in[7];
    const float* bn2g  = (const float*)d_in[8];
    const float* bn2b  = (const float*)d_in[9];
    const float* prow  = (const float*)d_in[10];
    const float* bn3g  = (const float*)d_in[11];
    const float* bn3b  = (const float*)d_in[12];
    const float* abng  = (const float*)d_in[13];
    const float* abnb  = (const float*)d_in[14];
    const float* projw = (const float*)d_in[15];
    const float* projb = (const float*)d_in[16];
    const float* ln2g  = (const float*)d_in[17];
    const float* ln2b  = (const float*)d_in[18];
    const float* fc1w  = (const float*)d_in[19];
    const float* fc1b  = (const float*)d_in[20];
    const float* fc2w  = (const float*)d_in[21];
    const float* fc2b  = (const float*)d_in[22];
    const float* scch  = (const float*)d_in[23];

    if (ws_size < WS_FLOATS * sizeof(float)) return;   // need ~107 MB scratch

    float* W     = (float*)d_ws;
    bf16*  hb    = (bf16*)(W + O_HB);     // h, then outm, then h2 (sequential)
    float* q     = W + O_Q;
    float* kx    = W + O_K;
    float* v     = W + O_V;
    float* att0  = W + O_ATT0;
    float* x1    = W + O_X1;
    bf16*  m1    = (bf16*)(W + O_ATT0);   // alias: att0 dead after k_p4
    bf16*  wqkvb = (bf16*)(W + O_WQKV);
    bf16*  wprjb = (bf16*)(W + O_WPRJ);
    bf16*  wfc1b = (bf16*)(W + O_WFC1);
    bf16*  wfc2b = (bf16*)(W + O_WFC2);
    float* stats = W + O_STATS;

    float* xout = (float*)d_out;
    float* datt = xout + XSIZE;

    hipMemsetAsync(stats, 0, ST_TOTAL * sizeof(float), stream);
    k_cvt<<<dim3(288, 4), 256, 0, stream>>>(qkvw, projw, fc1w, fc2w,
                                            wqkvb, wprjb, wfc1b, wfc2b);
    k_ln<<<NROWS, 384, 0, stream>>>(x, ln1g, ln1b, hb);
    k_qkv<<<dim3(9, 50), 256, 0, stream>>>(hb, wqkvb, q, kx, v);
    k_score<<<dim3(13, 384), 256, 0, stream>>>(q, kx, att0);
    k_moments<<<512, 256, 0, stream>>>(att0, stats);
    k_fin1<<<1, 64, 0, stream>>>(wexp, bn1g, bn1b, stats);
    k_sums2<<<dim3(15, 15, 32), 256, 0, stream>>>(att0, wexp, dww, stats, stats);
    k_fin2<<<1, 64, 0, stream>>>(bn2g, bn2b, stats);
    k_p3<<<dim3(15, 15, 32), 256, 0, stream>>>(att0, wexp, dww, prow, stats, datt);
    k_p3sums<<<512, 256, 0, stream>>>(datt, att0, stats);
    k_fin3<<<1, 64, 0, stream>>>(bn3g, bn3b, abng, abnb, stats);
    k_p4<<<dim3(13, 384), 256, 0, stream>>>(datt, att0, v, stats, hb);
    k_proj<<<dim3(3, 50), 256, 0, stream>>>(hb, wprjb, projb, x, x1);
    k_ln<<<NROWS, 384, 0, stream>>>(x1, ln2g, ln2b, hb);
    k_fc1<<<dim3(12, 50), 256, 0, stream>>>(hb, wfc1b, fc1b, m1);
    k_fc2<<<dim3(3, 50), 256, 0, stream>>>(m1, wfc2b, fc2b, scch, x1, xout);
}